// Round 14
// baseline (3465.270 us; speedup 1.0000x reference)
//
#include <hip/hip_runtime.h>
#include <math.h>

#define NN 50000
#define NE 800000
#define TE (NE + NN)
#define HC 128
#define NEG_SLOPE 0.2f
#define EPSV 1e-5f
#define NBUCK 64
#define GGRID 782          // (NN+63)/64 blocks for gemm_dual
#define WTB 128            // wtrans blocks
#define ZB 80              // zero blocks (grid-stride)
#define ZERO_N4 18645      // float4 count of zero region

typedef __attribute__((ext_vector_type(8))) short bf16x8;
typedef __attribute__((ext_vector_type(4))) float f32x4;
union BfU { uint4 u; bf16x8 b; };

__device__ __forceinline__ unsigned short f2bf(float x) {
    unsigned u = __float_as_uint(x);
    unsigned r = (u + 0x7fff + ((u >> 16) & 1)) >> 16;  // RNE
    return (unsigned short)r;
}

// ---------------- CSR build ----------------

__global__ __launch_bounds__(256) void count_k(const int* __restrict__ dst,
                                               int* __restrict__ cnt,
                                               int* __restrict__ rank) {
    int e = blockIdx.x * 256 + threadIdx.x;
    if (e >= TE) return;
    int d = (e < NE) ? dst[e] : (e - NE);
    rank[e] = atomicAdd(&cnt[d], 1);
}

__global__ __launch_bounds__(1024) void scan1_k(const int* __restrict__ cnt,
                                                int* __restrict__ excl,
                                                int* __restrict__ aux) {
    __shared__ int wsum[16];
    int tid = threadIdx.x;
    int gid = blockIdx.x * 1024 + tid;
    int lane = tid & 63, wid = tid >> 6;
    int v = (gid < NN) ? cnt[gid] : 0;
    int x = v;
#pragma unroll
    for (int off = 1; off < 64; off <<= 1) {
        int t = __shfl_up(x, off, 64);
        if (lane >= off) x += t;
    }
    if (lane == 63) wsum[wid] = x;
    __syncthreads();
    if (wid == 0 && lane < 16) {
        int y = wsum[lane];
#pragma unroll
        for (int off = 1; off < 16; off <<= 1) {
            int t = __shfl_up(y, off, 64);
            if (lane >= off) y += t;
        }
        wsum[lane] = y;
    }
    __syncthreads();
    int base = (wid > 0) ? wsum[wid - 1] : 0;
    int incl = base + x;
    if (gid < NN) excl[gid] = incl - v;
    if (tid == 1023) aux[blockIdx.x] = incl;
}

__global__ __launch_bounds__(256) void scatter_k(const int* __restrict__ srcp,
                                                 const int* __restrict__ dstp,
                                                 const int* __restrict__ excl,
                                                 const int* __restrict__ aux,
                                                 const int* __restrict__ rank,
                                                 int* __restrict__ row_ptr,
                                                 int* __restrict__ col,
                                                 int nblk) {
    __shared__ int auxs[64];
    if (threadIdx.x < 64) {
        int lane = threadIdx.x;
        int v = (lane < nblk) ? aux[lane] : 0;
        int x = v;
#pragma unroll
        for (int off = 1; off < 64; off <<= 1) {
            int t = __shfl_up(x, off, 64);
            if (lane >= off) x += t;
        }
        auxs[lane] = x - v;
    }
    __syncthreads();
    int e = blockIdx.x * 256 + threadIdx.x;
    if (e >= TE) return;
    if (e <= NN) row_ptr[e] = (e == NN) ? TE : excl[e] + auxs[e >> 10];
    int s, d;
    if (e < NE) { s = srcp[e]; d = dstp[e]; } else { s = e - NE; d = s; }
    col[excl[d] + auxs[d >> 10] + rank[e]] = s << 8;
}

// ---- packed xl epilogue store (fp32 path, layer 1) ----
__device__ __forceinline__ void store_xlp(char* xlp, int row, int c0, const float* a) {
    unsigned hsel = (unsigned)c0 >> 6;
    unsigned dd = (unsigned)c0 & 31;
    unsigned sub = (c0 & 32) ? 2u : 0u;
    char* q = xlp + (size_t)row * 256 + hsel * 128 + 4 * dd + sub;
#pragma unroll
    for (int j = 0; j < 4; ++j)
        *(unsigned short*)(q + 4 * j) = f2bf(a[j]);
}

// ---------------- init_k: gemm_dual (layer1) + wtrans + zero, block-range split ----------------

__global__ __launch_bounds__(256) void init_k(const float* __restrict__ x,
                                              const float* __restrict__ Wl1,
                                              const float* __restrict__ Wr1,
                                              char* __restrict__ xlp,
                                              float* __restrict__ xr,
                                              const float* __restrict__ Wl2,
                                              const float* __restrict__ Wr2,
                                              const float* __restrict__ Wl3,
                                              const float* __restrict__ Wr3,
                                              unsigned short* __restrict__ wt2,
                                              unsigned short* __restrict__ wt3,
                                              float4* __restrict__ zero4) {
    __shared__ float xs[32][72];
    __shared__ float ws[32][260];
    int b = blockIdx.x;
    int tid = threadIdx.x;

    if (b >= GGRID) {
        if (b < GGRID + WTB) {
            // W transpose: bf16 [col][k]
            int idx = (b - GGRID) * 256 + tid;
            int l = idx >> 14;
            int rem = idx & 16383;
            int k = rem >> 8;
            int c = rem & 255;
            const float* W = (l == 0) ? (c < 128 ? Wl2 : Wr2) : (c < 128 ? Wl3 : Wr3);
            float v = W[k * 128 + (c & 127)];
            unsigned short* wt = (l == 0) ? wt2 : wt3;
            wt[c * 64 + k] = f2bf(v);
        } else {
            // zero the stats/tickets/cnt region
            float4 zv; zv.x = zv.y = zv.z = zv.w = 0.f;
            for (int i = (b - GGRID - WTB) * 256 + tid; i < ZERO_N4; i += ZB * 256)
                zero4[i] = zv;
        }
        return;
    }

    // ---- gemm_dual body (K=3) ----
    int row0 = b * 64;
    int row_t = (tid >> 5) * 8;
    int c0 = (tid & 31) * 4;
    const int K = 3;

    float acc0[8][4];
    float acc1[8][4];
#pragma unroll
    for (int i = 0; i < 8; ++i)
#pragma unroll
        for (int j = 0; j < 4; ++j) { acc0[i][j] = 0.f; acc1[i][j] = 0.f; }

    for (int i = tid; i < 64 * K; i += 256) {
        int r = i / K;
        int k = i - r * K;
        int row = row0 + r;
        xs[k][r] = (row < NN) ? x[(size_t)row * K + k] : 0.f;
    }
    for (int i = tid; i < K * 64; i += 256) {
        int k = i >> 6;
        int cq = i & 63;
        const float* srcp = (cq < 32) ? &Wl1[(size_t)k * 128 + cq * 4]
                                      : &Wr1[(size_t)k * 128 + (cq - 32) * 4];
        float4 v = *(const float4*)srcp;
        *(float4*)&ws[k][cq * 4] = v;
    }
    __syncthreads();
    for (int k = 0; k < K; ++k) {
        float4 a0 = *(float4*)&xs[k][row_t];
        float4 a1 = *(float4*)&xs[k][row_t + 4];
        float4 b0 = *(float4*)&ws[k][c0];
        float4 b1 = *(float4*)&ws[k][c0 + 128];
        float av[8] = {a0.x, a0.y, a0.z, a0.w, a1.x, a1.y, a1.z, a1.w};
        float bl[4] = {b0.x, b0.y, b0.z, b0.w};
        float br[4] = {b1.x, b1.y, b1.z, b1.w};
#pragma unroll
        for (int i = 0; i < 8; ++i)
#pragma unroll
            for (int j = 0; j < 4; ++j) {
                acc0[i][j] += av[i] * bl[j];
                acc1[i][j] += av[i] * br[j];
            }
    }
#pragma unroll
    for (int i = 0; i < 8; ++i) {
        int row = row0 + row_t + i;
        if (row < NN) {
            store_xlp(xlp, row, c0, acc0[i]);
            float4 o1; o1.x = acc1[i][0]; o1.y = acc1[i][1]; o1.z = acc1[i][2]; o1.w = acc1[i][3];
            *(float4*)&xr[(size_t)row * HC + c0] = o1;
        }
    }
}

// ---------------- MFMA bf16 GEMM with fused graph-norm + ReLU input (K=64, layers 2,3) ----------------

__global__ __launch_bounds__(256) void gemm_mfma(const float* __restrict__ h,
                                                 const float* __restrict__ cf,
                                                 const unsigned short* __restrict__ wt,
                                                 char* __restrict__ xlp,
                                                 float* __restrict__ xr,
                                                 int n) {
    __shared__ unsigned short xs[64][72];
    int tid = threadIdx.x;
    int row0 = blockIdx.x * 64;

    {
        int r = tid >> 2;
        int q = tid & 3;
        int row = row0 + r;
        unsigned pk[8];
        if (row < n) {
            const float* hp = h + (size_t)row * 64 + q * 16;
#pragma unroll
            for (int i = 0; i < 4; ++i) {
                float4 v = *(const float4*)(hp + 4 * i);
                float4 cw = *(const float4*)&cf[q * 16 + 4 * i];
                float4 cb = *(const float4*)&cf[64 + q * 16 + 4 * i];
                float r0 = fmaxf(fmaf(cw.x, v.x, cb.x), 0.f);
                float r1 = fmaxf(fmaf(cw.y, v.y, cb.y), 0.f);
                float r2 = fmaxf(fmaf(cw.z, v.z, cb.z), 0.f);
                float r3 = fmaxf(fmaf(cw.w, v.w, cb.w), 0.f);
                pk[2 * i]     = (unsigned)f2bf(r0) | ((unsigned)f2bf(r1) << 16);
                pk[2 * i + 1] = (unsigned)f2bf(r2) | ((unsigned)f2bf(r3) << 16);
            }
        } else {
#pragma unroll
            for (int i = 0; i < 8; ++i) pk[i] = 0;
        }
        uint4* dst = (uint4*)&xs[r][q * 16];
        dst[0] = make_uint4(pk[0], pk[1], pk[2], pk[3]);
        dst[1] = make_uint4(pk[4], pk[5], pk[6], pk[7]);
    }
    __syncthreads();

    int w = tid >> 6;
    int lane = tid & 63;
    int m = lane & 15;
    int quad = lane >> 4;

    BfU a0, a1;
    a0.u = *(const uint4*)&xs[16 * w + m][quad * 8];
    a1.u = *(const uint4*)&xs[16 * w + m][32 + quad * 8];

    const char* wtb = (const char*)wt + (size_t)(m * 128 + quad * 16);

    f32x4 acc[16];
#pragma unroll
    for (int c = 0; c < 16; ++c) acc[c] = (f32x4){0.f, 0.f, 0.f, 0.f};
#pragma unroll
    for (int c = 0; c < 16; ++c) {
        BfU b0, b1;
        b0.u = *(const uint4*)(wtb + c * 2048);
        b1.u = *(const uint4*)(wtb + c * 2048 + 64);
        acc[c] = __builtin_amdgcn_mfma_f32_16x16x32_bf16(a0.b, b0.b, acc[c], 0, 0, 0);
        acc[c] = __builtin_amdgcn_mfma_f32_16x16x32_bf16(a1.b, b1.b, acc[c], 0, 0, 0);
    }

    int rbase = row0 + 16 * w + quad * 4;
#pragma unroll
    for (int c = 8; c < 16; ++c) {
        int colx = 16 * (c - 8) + m;
#pragma unroll
        for (int r = 0; r < 4; ++r) {
            int row = rbase + r;
            if (row < n) xr[(size_t)row * 128 + colx] = acc[c][r];
        }
    }
#pragma unroll
    for (int pi = 0; pi < 4; ++pi) {
        int c = (pi & 1) + (pi >> 1) * 4;
        int head = pi >> 1;
        int dd = (pi & 1) * 16 + m;
#pragma unroll
        for (int r = 0; r < 4; ++r) {
            int row = rbase + r;
            if (row < n) {
                unsigned val = (unsigned)f2bf(acc[c][r]) | ((unsigned)f2bf(acc[c + 2][r]) << 16);
                *(unsigned*)(xlp + (size_t)row * 256 + head * 128 + 4 * dd) = val;
            }
        }
    }
}

// ---------------- Attention + fused bucketed GraphNorm stats/coef ----------------
// Grid is exactly NN/4 -> no early return, all threads reach the epilogue barriers.
// Stats: 64 buckets x 128 floats; fan-in ~195/address (safe). Ticket-elected last
// block reduces buckets and writes cf.

__device__ __forceinline__ void attn_batch(const char* __restrict__ xlp, int lp4,
                                           const int* offs, float2 xrv,
                                           float2 c1, float2 c2,
                                           bool b16, int my, int rem,
                                           float& zacc, float2& o) {
    unsigned pk[8];
#pragma unroll
    for (int j = 0; j < 8; ++j)
        pk[j] = *(const unsigned*)(xlp + (unsigned)(offs[j] + lp4));
    float2 l[8];
#pragma unroll
    for (int j = 0; j < 8; ++j) {
        l[j].x = __uint_as_float(pk[j] << 16);
        l[j].y = __uint_as_float(pk[j] & 0xffff0000u);
    }
    float u[8];
#pragma unroll
    for (int j = 0; j < 8; ++j) {
        float2 t; t.x = l[j].x + xrv.x; t.y = l[j].y + xrv.y;
        float2 q;
        q.x = fmaf(c1.x, t.x, c2.x * fabsf(t.x));
        q.y = fmaf(c1.y, t.y, c2.y * fabsf(t.y));
        u[j] = q.x + q.y;
    }
#pragma unroll
    for (int j = 0; j < 8; ++j) u[j] += __shfl_xor(u[j], 16, 64);
    float w0 = b16 ? u[0] : u[1];
    float w1 = b16 ? u[2] : u[3];
    float w2 = b16 ? u[4] : u[5];
    float w3 = b16 ? u[6] : u[7];
#pragma unroll
    for (int off = 8; off > 0; off >>= 1) {
        w0 += __shfl_xor(w0, off, 64);
        w1 += __shfl_xor(w1, off, 64);
        w2 += __shfl_xor(w2, off, 64);
        w3 += __shfl_xor(w3, off, 64);
    }
    float e0 = __expf(w0);
    float e1 = __expf(w1);
    float e2 = __expf(w2);
    float e3 = __expf(w3);
    if (rem < 8) {
        if (my >= rem)     e0 = 0.f;
        if (2 + my >= rem) e1 = 0.f;
        if (4 + my >= rem) e2 = 0.f;
        if (6 + my >= rem) e3 = 0.f;
    }
    zacc += (e0 + e1) + (e2 + e3);
    float s0 = __shfl_xor(e0, 16, 64);
    float s1 = __shfl_xor(e1, 16, 64);
    float s2 = __shfl_xor(e2, 16, 64);
    float s3 = __shfl_xor(e3, 16, 64);
    float p0 = b16 ? e0 : s0;
    float p1 = b16 ? s0 : e0;
    float p2 = b16 ? e1 : s1;
    float p3 = b16 ? s1 : e1;
    float p4 = b16 ? e2 : s2;
    float p5 = b16 ? s2 : e2;
    float p6 = b16 ? e3 : s3;
    float p7 = b16 ? s3 : e3;
    o.x = fmaf(p0, l[0].x, o.x); o.y = fmaf(p0, l[0].y, o.y);
    o.x = fmaf(p1, l[1].x, o.x); o.y = fmaf(p1, l[1].y, o.y);
    o.x = fmaf(p2, l[2].x, o.x); o.y = fmaf(p2, l[2].y, o.y);
    o.x = fmaf(p3, l[3].x, o.x); o.y = fmaf(p3, l[3].y, o.y);
    o.x = fmaf(p4, l[4].x, o.x); o.y = fmaf(p4, l[4].y, o.y);
    o.x = fmaf(p5, l[5].x, o.x); o.y = fmaf(p5, l[5].y, o.y);
    o.x = fmaf(p6, l[6].x, o.x); o.y = fmaf(p6, l[6].y, o.y);
    o.x = fmaf(p7, l[7].x, o.x); o.y = fmaf(p7, l[7].y, o.y);
}

__global__ __launch_bounds__(256) void attn_k(const char* __restrict__ xlp,
                                              const float* __restrict__ xr,
                                              const float* __restrict__ att,
                                              const float* __restrict__ bias,
                                              const int* __restrict__ row_ptr,
                                              const int* __restrict__ coloff,
                                              float* __restrict__ hout,
                                              const float* __restrict__ gw,
                                              const float* __restrict__ gb,
                                              const float* __restrict__ gm,
                                              float* __restrict__ stats,
                                              int* __restrict__ ticket,
                                              float* __restrict__ cf) {
    __shared__ float sb[4][64];
    __shared__ float tot[2][128];
    __shared__ int lastFlag;
    int tid = threadIdx.x;
    int lane = tid & 63;
    int w = tid >> 6;
    int node = blockIdx.x * 4 + w;      // grid == NN/4 exactly
    int laneh = lane & 31;
    int lanebase = ((lane >> 5) << 8) | (laneh << 2);
    bool b16 = (lane & 16) == 0;
    int my = b16 ? 0 : 1;
    int lp4 = lane * 4;

    const char* xrc = (const char*)xr;
    unsigned nodeoff = (unsigned)node << 9;

    float2 xrv;
    xrv.x = *(const float*)(xrc + nodeoff + lanebase);
    xrv.y = *(const float*)(xrc + nodeoff + lanebase + 128);
    float a1 = att[lanebase >> 2];
    float a2 = att[(lanebase >> 2) + 32];
    float2 c1; c1.x = 0.6f * a1; c1.y = 0.6f * a2;
    float2 c2; c2.x = 0.4f * a1; c2.y = 0.4f * a2;

    float zacc = 0.f;
    float2 o; o.x = 0.f; o.y = 0.f;

    int beg = __builtin_amdgcn_readfirstlane(row_ptr[node]);
    int end = __builtin_amdgcn_readfirstlane(row_ptr[node + 1]);

    int idx = beg;
    for (; idx + 8 <= end; idx += 8) {
        int offs[8];
#pragma unroll
        for (int j = 0; j < 8; ++j) offs[j] = coloff[idx + j];
        attn_batch(xlp, lp4, offs, xrv, c1, c2, b16, my, 8, zacc, o);
    }
    if (idx < end) {
        int rem = end - idx;
        int end1 = end - 1;
        int offs[8];
#pragma unroll
        for (int j = 0; j < 8; ++j) offs[j] = coloff[min(idx + j, end1)];
        attn_batch(xlp, lp4, offs, xrv, c1, c2, b16, my, rem, zacc, o);
    }
    float z = zacc + __shfl_xor(zacc, 16, 64);
    float zi = 1.0f / z;
    float2 t; t.x = o.x * zi; t.y = o.y * zi;
    float u1 = __shfl_xor(t.x, 32, 64);
    float u2 = __shfl_xor(t.y, 32, 64);
    if (lane < 32) {
        float r1 = fmaf(0.5f, t.x + u1, bias[laneh]);
        float r2 = fmaf(0.5f, t.y + u2, bias[laneh + 32]);
        float* q = hout + (size_t)node * 64 + laneh;
        q[0] = r1;
        q[32] = r2;
        sb[w][laneh] = r1;
        sb[w][laneh + 32] = r2;
    }
    // ---- bucketed stats ----
    __syncthreads();
    if (tid < 64) {
        int c = tid;
        float v0 = sb[0][c], v1 = sb[1][c], v2 = sb[2][c], v3 = sb[3][c];
        float s = (v0 + v1) + (v2 + v3);
        float s2 = fmaf(v0, v0, v1 * v1) + fmaf(v2, v2, v3 * v3);
        float* bkt = stats + (blockIdx.x & (NBUCK - 1)) * 128;
        atomicAdd(&bkt[c], s);
        atomicAdd(&bkt[64 + c], s2);
    }
    __threadfence();
    if (tid == 0) {
        int tk = atomicAdd(ticket, 1);
        lastFlag = (tk == (int)gridDim.x - 1);
    }
    __syncthreads();
    if (!lastFlag) return;
    // last block: reduce buckets, write cf
    {
        int idx2 = tid & 127;
        int half = tid >> 7;          // 0..1, each handles 32 buckets
        float s = 0.f;
        for (int bkt = half * 32; bkt < half * 32 + 32; ++bkt)
            s += __hip_atomic_load(&stats[bkt * 128 + idx2], __ATOMIC_RELAXED, __HIP_MEMORY_SCOPE_AGENT);
        tot[half][idx2] = s;
    }
    __syncthreads();
    if (tid < 64) {
        int c = tid;
        float sum = tot[0][c] + tot[1][c];
        float sum2 = tot[0][64 + c] + tot[1][64 + c];
        float inv_n = 1.f / (float)NN;
        float mu = sum * inv_n;
        float ex2 = sum2 * inv_n;
        float g = gm[c];
        float var = ex2 - 2.f * g * mu * mu + g * g * mu * mu;
        float rs = rsqrtf(var + EPSV);
        cf[c] = gw[c] * rs;
        cf[64 + c] = gb[c] - gw[c] * rs * g * mu;
    }
}

// ---------------- final GraphNorm apply + ReLU (float4) ----------------

__global__ __launch_bounds__(256) void apply_k(const float* __restrict__ h,
                                               const float* __restrict__ cf,
                                               float* __restrict__ y) {
    int i = blockIdx.x * 256 + threadIdx.x;
    if (i >= NN * 16) return;
    int c = (i * 4) & 63;
    float4 v = *(const float4*)&h[(size_t)i * 4];
    float4 cw = *(const float4*)&cf[c];
    float4 cb = *(const float4*)&cf[64 + c];
    float4 r;
    r.x = fmaxf(fmaf(cw.x, v.x, cb.x), 0.f);
    r.y = fmaxf(fmaf(cw.y, v.y, cb.y), 0.f);
    r.z = fmaxf(fmaf(cw.z, v.z, cb.z), 0.f);
    r.w = fmaxf(fmaf(cw.w, v.w, cb.w), 0.f);
    *(float4*)&y[(size_t)i * 4] = r;
}

// ---------------- launch ----------------

extern "C" void kernel_launch(void* const* d_in, const int* in_sizes, int n_in,
                              void* d_out, int out_size, void* d_ws, size_t ws_size,
                              hipStream_t stream) {
    const float* x0 = (const float*)d_in[0];
    const int* ei = (const int*)d_in[1];
    const int* srcp = ei;
    const int* dstp = ei + NE;

    const float* Wl[3], *Wr[3], *att[3], *bv[3], *gw[3], *gb[3], *gm[3];
    for (int l = 0; l < 3; ++l) {
        int base = 2 + 7 * l;
        Wl[l] = (const float*)d_in[base + 0];
        Wr[l] = (const float*)d_in[base + 1];
        att[l] = (const float*)d_in[base + 2];
        bv[l] = (const float*)d_in[base + 3];
        gw[l] = (const float*)d_in[base + 4];
        gb[l] = (const float*)d_in[base + 5];
        gm[l] = (const float*)d_in[base + 6];
    }

    char* p = (char*)d_ws;
    auto take = [&](size_t bytes) -> void* {
        void* r = (void*)p;
        p += (bytes + 255) & ~(size_t)255;
        return r;
    };
    char* xlp = (char*)take((size_t)NN * 256);
    float* xr = (float*)take((size_t)NN * 128 * 4);
    float* hb = (float*)take((size_t)NN * 64 * 4);
    // zero region: stats buckets (3 * NBUCK * 128 f) + tickets (3 i + pad) + cnt (NN i)
    // = 98304 + 16 + 200000 = 298320 B = 18645 float4  (== ZERO_N4)
    char* zr = (char*)take(298320);
    float* stats = (float*)zr;                       // 3 * 64 * 128 floats
    int* tickets = (int*)(zr + 98304);
    int* cnt = (int*)(zr + 98320);
    int* excl = (int*)take((size_t)NN * 4);
    int* row_ptr = (int*)take((size_t)(NN + 1) * 4);
    int* rank = (int*)take((size_t)TE * 4);
    int* col = (int*)take((size_t)TE * 4);
    int* aux = (int*)take(64 * 4);
    float* cfb = (float*)take(3 * 128 * 4);
    unsigned short* wt2 = (unsigned short*)take(16384 * 2);
    unsigned short* wt3 = (unsigned short*)take(16384 * 2);

    int nblk = (NN + 1023) / 1024;
    int egrid = (TE + 255) / 256;

    // init: gemm_dual + wtrans + zero in one launch
    init_k<<<GGRID + WTB + ZB, 256, 0, stream>>>(x0, Wl[0], Wr[0], xlp, xr,
                                                 Wl[1], Wr[1], Wl[2], Wr[2],
                                                 wt2, wt3, (float4*)zr);
    count_k<<<egrid, 256, 0, stream>>>(dstp, cnt, rank);
    scan1_k<<<nblk, 1024, 0, stream>>>(cnt, excl, aux);
    scatter_k<<<egrid, 256, 0, stream>>>(srcp, dstp, excl, aux, rank, row_ptr, col, nblk);

    int ggrid = (NN + 63) / 64;
    int agrid = NN / 4;   // exact: all blocks full
    for (int l = 0; l < 3; ++l) {
        float* cf = cfb + l * 128;
        if (l > 0)
            gemm_mfma<<<ggrid, 256, 0, stream>>>(hb, cfb + (l - 1) * 128,
                                                 (l == 1) ? wt2 : wt3, xlp, xr, NN);
        attn_k<<<agrid, 256, 0, stream>>>(xlp, xr, att[l], bv[l], row_ptr, col, hb,
                                          gw[l], gb[l], gm[l],
                                          stats + l * NBUCK * 128, tickets + l, cf);
    }
    apply_k<<<(NN * 16 + 255) / 256, 256, 0, stream>>>(hb, cfb + 2 * 128, (float*)d_out);
}

// Round 15
// 439.034 us; speedup vs baseline: 7.8929x; 7.8929x over previous
//
#include <hip/hip_runtime.h>
#include <math.h>

#define NN 50000
#define NE 800000
#define TE (NE + NN)
#define HC 128
#define NEG_SLOPE 0.2f
#define EPSV 1e-5f
#define STATS_BLOCKS 256
#define GGRID 782          // (NN+63)/64 blocks for gemm_dual part of init_k
#define WTB 128            // wtrans blocks
#define ZB 52              // zero blocks
#define ZERO_N4 12597      // float4 count of zero region (201552 B)

typedef __attribute__((ext_vector_type(8))) short bf16x8;
typedef __attribute__((ext_vector_type(4))) float f32x4;
union BfU { uint4 u; bf16x8 b; };

__device__ __forceinline__ unsigned short f2bf(float x) {
    unsigned u = __float_as_uint(x);
    unsigned r = (u + 0x7fff + ((u >> 16) & 1)) >> 16;  // RNE
    return (unsigned short)r;
}

// ---------------- CSR build ----------------

__global__ __launch_bounds__(256) void count_k(const int* __restrict__ dst,
                                               int* __restrict__ cnt,
                                               int* __restrict__ rank) {
    int e = blockIdx.x * 256 + threadIdx.x;
    if (e >= TE) return;
    int d = (e < NE) ? dst[e] : (e - NE);
    rank[e] = atomicAdd(&cnt[d], 1);
}

__global__ __launch_bounds__(1024) void scan1_k(const int* __restrict__ cnt,
                                                int* __restrict__ excl,
                                                int* __restrict__ aux) {
    __shared__ int wsum[16];
    int tid = threadIdx.x;
    int gid = blockIdx.x * 1024 + tid;
    int lane = tid & 63, wid = tid >> 6;
    int v = (gid < NN) ? cnt[gid] : 0;
    int x = v;
#pragma unroll
    for (int off = 1; off < 64; off <<= 1) {
        int t = __shfl_up(x, off, 64);
        if (lane >= off) x += t;
    }
    if (lane == 63) wsum[wid] = x;
    __syncthreads();
    if (wid == 0 && lane < 16) {
        int y = wsum[lane];
#pragma unroll
        for (int off = 1; off < 16; off <<= 1) {
            int t = __shfl_up(y, off, 64);
            if (lane >= off) y += t;
        }
        wsum[lane] = y;
    }
    __syncthreads();
    int base = (wid > 0) ? wsum[wid - 1] : 0;
    int incl = base + x;
    if (gid < NN) excl[gid] = incl - v;
    if (tid == 1023) aux[blockIdx.x] = incl;
}

__global__ __launch_bounds__(256) void scatter_k(const int* __restrict__ srcp,
                                                 const int* __restrict__ dstp,
                                                 const int* __restrict__ excl,
                                                 const int* __restrict__ aux,
                                                 const int* __restrict__ rank,
                                                 int* __restrict__ row_ptr,
                                                 int* __restrict__ col,
                                                 int nblk) {
    __shared__ int auxs[64];
    if (threadIdx.x < 64) {
        int lane = threadIdx.x;
        int v = (lane < nblk) ? aux[lane] : 0;
        int x = v;
#pragma unroll
        for (int off = 1; off < 64; off <<= 1) {
            int t = __shfl_up(x, off, 64);
            if (lane >= off) x += t;
        }
        auxs[lane] = x - v;
    }
    __syncthreads();
    int e = blockIdx.x * 256 + threadIdx.x;
    if (e >= TE) return;
    if (e <= NN) row_ptr[e] = (e == NN) ? TE : excl[e] + auxs[e >> 10];
    int s, d;
    if (e < NE) { s = srcp[e]; d = dstp[e]; } else { s = e - NE; d = s; }
    col[excl[d] + auxs[d >> 10] + rank[e]] = s << 8;
}

// ---- packed xl epilogue store (fp32 path, layer 1) ----
__device__ __forceinline__ void store_xlp(char* xlp, int row, int c0, const float* a) {
    unsigned hsel = (unsigned)c0 >> 6;
    unsigned dd = (unsigned)c0 & 31;
    unsigned sub = (c0 & 32) ? 2u : 0u;
    char* q = xlp + (size_t)row * 256 + hsel * 128 + 4 * dd + sub;
#pragma unroll
    for (int j = 0; j < 4; ++j)
        *(unsigned short*)(q + 4 * j) = f2bf(a[j]);
}

// ---------------- init_k: gemm_dual (layer1) + wtrans + zero, block-range split ----------------

__global__ __launch_bounds__(256) void init_k(const float* __restrict__ x,
                                              const float* __restrict__ Wl1,
                                              const float* __restrict__ Wr1,
                                              char* __restrict__ xlp,
                                              float* __restrict__ xr,
                                              const float* __restrict__ Wl2,
                                              const float* __restrict__ Wr2,
                                              const float* __restrict__ Wl3,
                                              const float* __restrict__ Wr3,
                                              unsigned short* __restrict__ wt2,
                                              unsigned short* __restrict__ wt3,
                                              float4* __restrict__ zero4) {
    __shared__ float xs[32][72];
    __shared__ float ws[32][260];
    int b = blockIdx.x;
    int tid = threadIdx.x;

    if (b >= GGRID) {
        if (b < GGRID + WTB) {
            int idx = (b - GGRID) * 256 + tid;
            int l = idx >> 14;
            int rem = idx & 16383;
            int k = rem >> 8;
            int c = rem & 255;
            const float* W = (l == 0) ? (c < 128 ? Wl2 : Wr2) : (c < 128 ? Wl3 : Wr3);
            float v = W[k * 128 + (c & 127)];
            unsigned short* wt = (l == 0) ? wt2 : wt3;
            wt[c * 64 + k] = f2bf(v);
        } else {
            float4 zv; zv.x = zv.y = zv.z = zv.w = 0.f;
            for (int i = (b - GGRID - WTB) * 256 + tid; i < ZERO_N4; i += ZB * 256)
                zero4[i] = zv;
        }
        return;
    }

    // ---- gemm_dual body (K=3) ----
    int row0 = b * 64;
    int row_t = (tid >> 5) * 8;
    int c0 = (tid & 31) * 4;
    const int K = 3;

    float acc0[8][4];
    float acc1[8][4];
#pragma unroll
    for (int i = 0; i < 8; ++i)
#pragma unroll
        for (int j = 0; j < 4; ++j) { acc0[i][j] = 0.f; acc1[i][j] = 0.f; }

    for (int i = tid; i < 64 * K; i += 256) {
        int r = i / K;
        int k = i - r * K;
        int row = row0 + r;
        xs[k][r] = (row < NN) ? x[(size_t)row * K + k] : 0.f;
    }
    for (int i = tid; i < K * 64; i += 256) {
        int k = i >> 6;
        int cq = i & 63;
        const float* srcp = (cq < 32) ? &Wl1[(size_t)k * 128 + cq * 4]
                                      : &Wr1[(size_t)k * 128 + (cq - 32) * 4];
        float4 v = *(const float4*)srcp;
        *(float4*)&ws[k][cq * 4] = v;
    }
    __syncthreads();
    for (int k = 0; k < K; ++k) {
        float4 a0 = *(float4*)&xs[k][row_t];
        float4 a1 = *(float4*)&xs[k][row_t + 4];
        float4 b0 = *(float4*)&ws[k][c0];
        float4 b1 = *(float4*)&ws[k][c0 + 128];
        float av[8] = {a0.x, a0.y, a0.z, a0.w, a1.x, a1.y, a1.z, a1.w};
        float bl[4] = {b0.x, b0.y, b0.z, b0.w};
        float br[4] = {b1.x, b1.y, b1.z, b1.w};
#pragma unroll
        for (int i = 0; i < 8; ++i)
#pragma unroll
            for (int j = 0; j < 4; ++j) {
                acc0[i][j] += av[i] * bl[j];
                acc1[i][j] += av[i] * br[j];
            }
    }
#pragma unroll
    for (int i = 0; i < 8; ++i) {
        int row = row0 + row_t + i;
        if (row < NN) {
            store_xlp(xlp, row, c0, acc0[i]);
            float4 o1; o1.x = acc1[i][0]; o1.y = acc1[i][1]; o1.z = acc1[i][2]; o1.w = acc1[i][3];
            *(float4*)&xr[(size_t)row * HC + c0] = o1;
        }
    }
}

// ---------------- MFMA bf16 GEMM with fused graph-norm + ReLU input (K=64, layers 2,3) ----------------

__global__ __launch_bounds__(256) void gemm_mfma(const float* __restrict__ h,
                                                 const float* __restrict__ cf,
                                                 const unsigned short* __restrict__ wt,
                                                 char* __restrict__ xlp,
                                                 float* __restrict__ xr,
                                                 int n) {
    __shared__ unsigned short xs[64][72];
    int tid = threadIdx.x;
    int row0 = blockIdx.x * 64;

    {
        int r = tid >> 2;
        int q = tid & 3;
        int row = row0 + r;
        unsigned pk[8];
        if (row < n) {
            const float* hp = h + (size_t)row * 64 + q * 16;
#pragma unroll
            for (int i = 0; i < 4; ++i) {
                float4 v = *(const float4*)(hp + 4 * i);
                float4 cw = *(const float4*)&cf[q * 16 + 4 * i];
                float4 cb = *(const float4*)&cf[64 + q * 16 + 4 * i];
                float r0 = fmaxf(fmaf(cw.x, v.x, cb.x), 0.f);
                float r1 = fmaxf(fmaf(cw.y, v.y, cb.y), 0.f);
                float r2 = fmaxf(fmaf(cw.z, v.z, cb.z), 0.f);
                float r3 = fmaxf(fmaf(cw.w, v.w, cb.w), 0.f);
                pk[2 * i]     = (unsigned)f2bf(r0) | ((unsigned)f2bf(r1) << 16);
                pk[2 * i + 1] = (unsigned)f2bf(r2) | ((unsigned)f2bf(r3) << 16);
            }
        } else {
#pragma unroll
            for (int i = 0; i < 8; ++i) pk[i] = 0;
        }
        uint4* dst = (uint4*)&xs[r][q * 16];
        dst[0] = make_uint4(pk[0], pk[1], pk[2], pk[3]);
        dst[1] = make_uint4(pk[4], pk[5], pk[6], pk[7]);
    }
    __syncthreads();

    int w = tid >> 6;
    int lane = tid & 63;
    int m = lane & 15;
    int quad = lane >> 4;

    BfU a0, a1;
    a0.u = *(const uint4*)&xs[16 * w + m][quad * 8];
    a1.u = *(const uint4*)&xs[16 * w + m][32 + quad * 8];

    const char* wtb = (const char*)wt + (size_t)(m * 128 + quad * 16);

    f32x4 acc[16];
#pragma unroll
    for (int c = 0; c < 16; ++c) acc[c] = (f32x4){0.f, 0.f, 0.f, 0.f};
#pragma unroll
    for (int c = 0; c < 16; ++c) {
        BfU b0, b1;
        b0.u = *(const uint4*)(wtb + c * 2048);
        b1.u = *(const uint4*)(wtb + c * 2048 + 64);
        acc[c] = __builtin_amdgcn_mfma_f32_16x16x32_bf16(a0.b, b0.b, acc[c], 0, 0, 0);
        acc[c] = __builtin_amdgcn_mfma_f32_16x16x32_bf16(a1.b, b1.b, acc[c], 0, 0, 0);
    }

    int rbase = row0 + 16 * w + quad * 4;
#pragma unroll
    for (int c = 8; c < 16; ++c) {
        int colx = 16 * (c - 8) + m;
#pragma unroll
        for (int r = 0; r < 4; ++r) {
            int row = rbase + r;
            if (row < n) xr[(size_t)row * 128 + colx] = acc[c][r];
        }
    }
#pragma unroll
    for (int pi = 0; pi < 4; ++pi) {
        int c = (pi & 1) + (pi >> 1) * 4;
        int head = pi >> 1;
        int dd = (pi & 1) * 16 + m;
#pragma unroll
        for (int r = 0; r < 4; ++r) {
            int row = rbase + r;
            if (row < n) {
                unsigned val = (unsigned)f2bf(acc[c][r]) | ((unsigned)f2bf(acc[c + 2][r]) << 16);
                *(unsigned*)(xlp + (size_t)row * 256 + head * 128 + 4 * dd) = val;
            }
        }
    }
}

// ---------------- Attention (R12/R13-proven) ----------------

__device__ __forceinline__ void attn_batch(const char* __restrict__ xlp, int lp4,
                                           const int* offs, float2 xrv,
                                           float2 c1, float2 c2,
                                           bool b16, int my, int rem,
                                           float& zacc, float2& o) {
    unsigned pk[8];
#pragma unroll
    for (int j = 0; j < 8; ++j)
        pk[j] = *(const unsigned*)(xlp + (unsigned)(offs[j] + lp4));
    float2 l[8];
#pragma unroll
    for (int j = 0; j < 8; ++j) {
        l[j].x = __uint_as_float(pk[j] << 16);
        l[j].y = __uint_as_float(pk[j] & 0xffff0000u);
    }
    float u[8];
#pragma unroll
    for (int j = 0; j < 8; ++j) {
        float2 t; t.x = l[j].x + xrv.x; t.y = l[j].y + xrv.y;
        float2 q;
        q.x = fmaf(c1.x, t.x, c2.x * fabsf(t.x));
        q.y = fmaf(c1.y, t.y, c2.y * fabsf(t.y));
        u[j] = q.x + q.y;
    }
#pragma unroll
    for (int j = 0; j < 8; ++j) u[j] += __shfl_xor(u[j], 16, 64);
    float w0 = b16 ? u[0] : u[1];
    float w1 = b16 ? u[2] : u[3];
    float w2 = b16 ? u[4] : u[5];
    float w3 = b16 ? u[6] : u[7];
#pragma unroll
    for (int off = 8; off > 0; off >>= 1) {
        w0 += __shfl_xor(w0, off, 64);
        w1 += __shfl_xor(w1, off, 64);
        w2 += __shfl_xor(w2, off, 64);
        w3 += __shfl_xor(w3, off, 64);
    }
    float e0 = __expf(w0);
    float e1 = __expf(w1);
    float e2 = __expf(w2);
    float e3 = __expf(w3);
    if (rem < 8) {
        if (my >= rem)     e0 = 0.f;
        if (2 + my >= rem) e1 = 0.f;
        if (4 + my >= rem) e2 = 0.f;
        if (6 + my >= rem) e3 = 0.f;
    }
    zacc += (e0 + e1) + (e2 + e3);
    float s0 = __shfl_xor(e0, 16, 64);
    float s1 = __shfl_xor(e1, 16, 64);
    float s2 = __shfl_xor(e2, 16, 64);
    float s3 = __shfl_xor(e3, 16, 64);
    float p0 = b16 ? e0 : s0;
    float p1 = b16 ? s0 : e0;
    float p2 = b16 ? e1 : s1;
    float p3 = b16 ? s1 : e1;
    float p4 = b16 ? e2 : s2;
    float p5 = b16 ? s2 : e2;
    float p6 = b16 ? e3 : s3;
    float p7 = b16 ? s3 : e3;
    o.x = fmaf(p0, l[0].x, o.x); o.y = fmaf(p0, l[0].y, o.y);
    o.x = fmaf(p1, l[1].x, o.x); o.y = fmaf(p1, l[1].y, o.y);
    o.x = fmaf(p2, l[2].x, o.x); o.y = fmaf(p2, l[2].y, o.y);
    o.x = fmaf(p3, l[3].x, o.x); o.y = fmaf(p3, l[3].y, o.y);
    o.x = fmaf(p4, l[4].x, o.x); o.y = fmaf(p4, l[4].y, o.y);
    o.x = fmaf(p5, l[5].x, o.x); o.y = fmaf(p5, l[5].y, o.y);
    o.x = fmaf(p6, l[6].x, o.x); o.y = fmaf(p6, l[6].y, o.y);
    o.x = fmaf(p7, l[7].x, o.x); o.y = fmaf(p7, l[7].y, o.y);
}

__global__ __launch_bounds__(256) void attn_k(const char* __restrict__ xlp,
                                              const float* __restrict__ xr,
                                              const float* __restrict__ att,
                                              const float* __restrict__ bias,
                                              const int* __restrict__ row_ptr,
                                              const int* __restrict__ coloff,
                                              float* __restrict__ hout) {
    int lane = threadIdx.x & 63;
    int node = blockIdx.x * 4 + (threadIdx.x >> 6);
    if (node >= NN) return;
    int laneh = lane & 31;
    int lanebase = ((lane >> 5) << 8) | (laneh << 2);
    bool b16 = (lane & 16) == 0;
    int my = b16 ? 0 : 1;
    int lp4 = lane * 4;

    const char* xrc = (const char*)xr;
    unsigned nodeoff = (unsigned)node << 9;

    float2 xrv;
    xrv.x = *(const float*)(xrc + nodeoff + lanebase);
    xrv.y = *(const float*)(xrc + nodeoff + lanebase + 128);
    float a1 = att[lanebase >> 2];
    float a2 = att[(lanebase >> 2) + 32];
    float2 c1; c1.x = 0.6f * a1; c1.y = 0.6f * a2;
    float2 c2; c2.x = 0.4f * a1; c2.y = 0.4f * a2;

    float zacc = 0.f;
    float2 o; o.x = 0.f; o.y = 0.f;

    int beg = __builtin_amdgcn_readfirstlane(row_ptr[node]);
    int end = __builtin_amdgcn_readfirstlane(row_ptr[node + 1]);

    int idx = beg;
    for (; idx + 8 <= end; idx += 8) {
        int offs[8];
#pragma unroll
        for (int j = 0; j < 8; ++j) offs[j] = coloff[idx + j];
        attn_batch(xlp, lp4, offs, xrv, c1, c2, b16, my, 8, zacc, o);
    }
    if (idx < end) {
        int rem = end - idx;
        int end1 = end - 1;
        int offs[8];
#pragma unroll
        for (int j = 0; j < 8; ++j) offs[j] = coloff[min(idx + j, end1)];
        attn_batch(xlp, lp4, offs, xrv, c1, c2, b16, my, rem, zacc, o);
    }
    float z = zacc + __shfl_xor(zacc, 16, 64);
    float zi = 1.0f / z;
    float2 t; t.x = o.x * zi; t.y = o.y * zi;
    float u1 = __shfl_xor(t.x, 32, 64);
    float u2 = __shfl_xor(t.y, 32, 64);
    if (lane < 32) {
        float r1 = fmaf(0.5f, t.x + u1, bias[laneh]);
        float r2 = fmaf(0.5f, t.y + u2, bias[laneh + 32]);
        float* q = hout + (size_t)node * 64 + laneh;
        q[0] = r1;
        q[32] = r2;
    }
}

// ---------------- GraphNorm stats + coefficient (256-block fan-in, safe) ----------------

__global__ __launch_bounds__(256) void colstats_k(const float* __restrict__ h,
                                                  const float* __restrict__ gw,
                                                  const float* __restrict__ gb,
                                                  const float* __restrict__ gm,
                                                  float* __restrict__ stats,
                                                  int* __restrict__ ticket,
                                                  float* __restrict__ cf) {
    int c = threadIdx.x & 63;
    int rg = threadIdx.x >> 6;
    float s = 0.f, s2 = 0.f;
    for (int r = blockIdx.x * 4 + rg; r < NN; r += gridDim.x * 4) {
        float v = h[(size_t)r * 64 + c];
        s += v;
        s2 += v * v;
    }
    __shared__ float b1[4][64];
    __shared__ float b2[4][64];
    b1[rg][c] = s;
    b2[rg][c] = s2;
    __syncthreads();
    if (threadIdx.x < 64) {
        s = b1[0][c] + b1[1][c] + b1[2][c] + b1[3][c];
        s2 = b2[0][c] + b2[1][c] + b2[2][c] + b2[3][c];
        atomicAdd(&stats[c], s);
        atomicAdd(&stats[64 + c], s2);
    }
    __shared__ int lastFlag;
    __threadfence();
    if (threadIdx.x == 0) {
        int t = atomicAdd(ticket, 1);
        lastFlag = (t == (int)gridDim.x - 1);
    }
    __syncthreads();
    if (lastFlag && threadIdx.x < 64) {
        float sum = __hip_atomic_load(&stats[c], __ATOMIC_RELAXED, __HIP_MEMORY_SCOPE_AGENT);
        float sum2 = __hip_atomic_load(&stats[64 + c], __ATOMIC_RELAXED, __HIP_MEMORY_SCOPE_AGENT);
        float inv_n = 1.f / (float)NN;
        float mu = sum * inv_n;
        float ex2 = sum2 * inv_n;
        float g = gm[c];
        float var = ex2 - 2.f * g * mu * mu + g * g * mu * mu;
        float rs = rsqrtf(var + EPSV);
        cf[c] = gw[c] * rs;
        cf[64 + c] = gb[c] - gw[c] * rs * g * mu;
    }
}

// ---------------- final GraphNorm apply + ReLU (float4) ----------------

__global__ __launch_bounds__(256) void apply_k(const float* __restrict__ h,
                                               const float* __restrict__ cf,
                                               float* __restrict__ y) {
    int i = blockIdx.x * 256 + threadIdx.x;
    if (i >= NN * 16) return;
    int c = (i * 4) & 63;
    float4 v = *(const float4*)&h[(size_t)i * 4];
    float4 cw = *(const float4*)&cf[c];
    float4 cb = *(const float4*)&cf[64 + c];
    float4 r;
    r.x = fmaxf(fmaf(cw.x, v.x, cb.x), 0.f);
    r.y = fmaxf(fmaf(cw.y, v.y, cb.y), 0.f);
    r.z = fmaxf(fmaf(cw.z, v.z, cb.z), 0.f);
    r.w = fmaxf(fmaf(cw.w, v.w, cb.w), 0.f);
    *(float4*)&y[(size_t)i * 4] = r;
}

// ---------------- launch ----------------

extern "C" void kernel_launch(void* const* d_in, const int* in_sizes, int n_in,
                              void* d_out, int out_size, void* d_ws, size_t ws_size,
                              hipStream_t stream) {
    const float* x0 = (const float*)d_in[0];
    const int* ei = (const int*)d_in[1];
    const int* srcp = ei;
    const int* dstp = ei + NE;

    const float* Wl[3], *Wr[3], *att[3], *bv[3], *gw[3], *gb[3], *gm[3];
    for (int l = 0; l < 3; ++l) {
        int base = 2 + 7 * l;
        Wl[l] = (const float*)d_in[base + 0];
        Wr[l] = (const float*)d_in[base + 1];
        att[l] = (const float*)d_in[base + 2];
        bv[l] = (const float*)d_in[base + 3];
        gw[l] = (const float*)d_in[base + 4];
        gb[l] = (const float*)d_in[base + 5];
        gm[l] = (const float*)d_in[base + 6];
    }

    char* p = (char*)d_ws;
    auto take = [&](size_t bytes) -> void* {
        void* r = (void*)p;
        p += (bytes + 255) & ~(size_t)255;
        return r;
    };
    char* xlp = (char*)take((size_t)NN * 256);
    float* xr = (float*)take((size_t)NN * 128 * 4);
    float* hb = (float*)take((size_t)NN * 64 * 4);
    // zero region: stats (3*128 f = 1536 B) + tickets (12 B -> pad 16) + cnt (200000 B)
    // = 201552 B = 12597 float4  (== ZERO_N4)
    char* zr = (char*)take(201552);
    float* stats = (float*)zr;
    int* tickets = (int*)(zr + 1536);
    int* cnt = (int*)(zr + 1552);
    int* excl = (int*)take((size_t)NN * 4);
    int* row_ptr = (int*)take((size_t)(NN + 1) * 4);
    int* rank = (int*)take((size_t)TE * 4);
    int* col = (int*)take((size_t)TE * 4);
    int* aux = (int*)take(64 * 4);
    float* cfb = (float*)take(3 * 128 * 4);
    unsigned short* wt2 = (unsigned short*)take(16384 * 2);
    unsigned short* wt3 = (unsigned short*)take(16384 * 2);

    int nblk = (NN + 1023) / 1024;
    int egrid = (TE + 255) / 256;

    init_k<<<GGRID + WTB + ZB, 256, 0, stream>>>(x0, Wl[0], Wr[0], xlp, xr,
                                                 Wl[1], Wr[1], Wl[2], Wr[2],
                                                 wt2, wt3, (float4*)zr);
    count_k<<<egrid, 256, 0, stream>>>(dstp, cnt, rank);
    scan1_k<<<nblk, 1024, 0, stream>>>(cnt, excl, aux);
    scatter_k<<<egrid, 256, 0, stream>>>(srcp, dstp, excl, aux, rank, row_ptr, col, nblk);

    int ggrid = (NN + 63) / 64;
    int agrid = (NN + 3) / 4;
    for (int l = 0; l < 3; ++l) {
        float* cf = cfb + l * 128;
        if (l > 0)
            gemm_mfma<<<ggrid, 256, 0, stream>>>(hb, cfb + (l - 1) * 128,
                                                 (l == 1) ? wt2 : wt3, xlp, xr, NN);
        attn_k<<<agrid, 256, 0, stream>>>(xlp, xr, att[l], bv[l], row_ptr, col, hb);
        colstats_k<<<STATS_BLOCKS, 256, 0, stream>>>(hb, gw[l], gb[l], gm[l],
                                                     stats + l * 128, tickets + l, cf);
    }
    apply_k<<<(NN * 16 + 255) / 256, 256, 0, stream>>>(hb, cfb + 2 * 128, (float*)d_out);
}

// Round 16
// 361.780 us; speedup vs baseline: 9.5784x; 1.2135x over previous
//
#include <hip/hip_runtime.h>
#include <math.h>

#define NN 50000
#define NE 800000
#define TE (NE + NN)
#define HC 128
#define NEG_SLOPE 0.2f
#define EPSV 1e-5f
#define NBUCK 64
#define GGRID 782          // (NN+63)/64 blocks for gemm_dual part of init_k
#define WTB 128            // wtrans blocks
#define ZB 52              // zero blocks
#define ZERO_N4 18644      // float4 count of zero region (298304 B = stats 98304 + cnt 200000)

typedef __attribute__((ext_vector_type(8))) short bf16x8;
typedef __attribute__((ext_vector_type(4))) float f32x4;
union BfU { uint4 u; bf16x8 b; };

__device__ __forceinline__ unsigned short f2bf(float x) {
    unsigned u = __float_as_uint(x);
    unsigned r = (u + 0x7fff + ((u >> 16) & 1)) >> 16;  // RNE
    return (unsigned short)r;
}

// ---------------- CSR build ----------------

__global__ __launch_bounds__(256) void count_k(const int* __restrict__ dst,
                                               int* __restrict__ cnt,
                                               int* __restrict__ rank) {
    int e = blockIdx.x * 256 + threadIdx.x;
    if (e >= TE) return;
    int d = (e < NE) ? dst[e] : (e - NE);
    rank[e] = atomicAdd(&cnt[d], 1);
}

__global__ __launch_bounds__(1024) void scan1_k(const int* __restrict__ cnt,
                                                int* __restrict__ excl,
                                                int* __restrict__ aux) {
    __shared__ int wsum[16];
    int tid = threadIdx.x;
    int gid = blockIdx.x * 1024 + tid;
    int lane = tid & 63, wid = tid >> 6;
    int v = (gid < NN) ? cnt[gid] : 0;
    int x = v;
#pragma unroll
    for (int off = 1; off < 64; off <<= 1) {
        int t = __shfl_up(x, off, 64);
        if (lane >= off) x += t;
    }
    if (lane == 63) wsum[wid] = x;
    __syncthreads();
    if (wid == 0 && lane < 16) {
        int y = wsum[lane];
#pragma unroll
        for (int off = 1; off < 16; off <<= 1) {
            int t = __shfl_up(y, off, 64);
            if (lane >= off) y += t;
        }
        wsum[lane] = y;
    }
    __syncthreads();
    int base = (wid > 0) ? wsum[wid - 1] : 0;
    int incl = base + x;
    if (gid < NN) excl[gid] = incl - v;
    if (tid == 1023) aux[blockIdx.x] = incl;
}

__global__ __launch_bounds__(256) void scatter_k(const int* __restrict__ srcp,
                                                 const int* __restrict__ dstp,
                                                 const int* __restrict__ excl,
                                                 const int* __restrict__ aux,
                                                 const int* __restrict__ rank,
                                                 int* __restrict__ row_ptr,
                                                 int* __restrict__ col,
                                                 int nblk) {
    __shared__ int auxs[64];
    if (threadIdx.x < 64) {
        int lane = threadIdx.x;
        int v = (lane < nblk) ? aux[lane] : 0;
        int x = v;
#pragma unroll
        for (int off = 1; off < 64; off <<= 1) {
            int t = __shfl_up(x, off, 64);
            if (lane >= off) x += t;
        }
        auxs[lane] = x - v;
    }
    __syncthreads();
    int e = blockIdx.x * 256 + threadIdx.x;
    if (e >= TE) return;
    if (e <= NN) row_ptr[e] = (e == NN) ? TE : excl[e] + auxs[e >> 10];
    int s, d;
    if (e < NE) { s = srcp[e]; d = dstp[e]; } else { s = e - NE; d = s; }
    col[excl[d] + auxs[d >> 10] + rank[e]] = s << 8;
}

// ---- packed xl epilogue store (fp32 path, layer 1) ----
__device__ __forceinline__ void store_xlp(char* xlp, int row, int c0, const float* a) {
    unsigned hsel = (unsigned)c0 >> 6;
    unsigned dd = (unsigned)c0 & 31;
    unsigned sub = (c0 & 32) ? 2u : 0u;
    char* q = xlp + (size_t)row * 256 + hsel * 128 + 4 * dd + sub;
#pragma unroll
    for (int j = 0; j < 4; ++j)
        *(unsigned short*)(q + 4 * j) = f2bf(a[j]);
}

// ---------------- init_k: gemm_dual (layer1) + wtrans + zero, block-range split ----------------

__global__ __launch_bounds__(256) void init_k(const float* __restrict__ x,
                                              const float* __restrict__ Wl1,
                                              const float* __restrict__ Wr1,
                                              char* __restrict__ xlp,
                                              float* __restrict__ xr,
                                              const float* __restrict__ Wl2,
                                              const float* __restrict__ Wr2,
                                              const float* __restrict__ Wl3,
                                              const float* __restrict__ Wr3,
                                              unsigned short* __restrict__ wt2,
                                              unsigned short* __restrict__ wt3,
                                              float4* __restrict__ zero4) {
    __shared__ float xs[32][72];
    __shared__ float ws[32][260];
    int b = blockIdx.x;
    int tid = threadIdx.x;

    if (b >= GGRID) {
        if (b < GGRID + WTB) {
            int idx = (b - GGRID) * 256 + tid;
            int l = idx >> 14;
            int rem = idx & 16383;
            int k = rem >> 8;
            int c = rem & 255;
            const float* W = (l == 0) ? (c < 128 ? Wl2 : Wr2) : (c < 128 ? Wl3 : Wr3);
            float v = W[k * 128 + (c & 127)];
            unsigned short* wt = (l == 0) ? wt2 : wt3;
            wt[c * 64 + k] = f2bf(v);
        } else {
            float4 zv; zv.x = zv.y = zv.z = zv.w = 0.f;
            for (int i = (b - GGRID - WTB) * 256 + tid; i < ZERO_N4; i += ZB * 256)
                zero4[i] = zv;
        }
        return;
    }

    // ---- gemm_dual body (K=3) ----
    int row0 = b * 64;
    int row_t = (tid >> 5) * 8;
    int c0 = (tid & 31) * 4;
    const int K = 3;

    float acc0[8][4];
    float acc1[8][4];
#pragma unroll
    for (int i = 0; i < 8; ++i)
#pragma unroll
        for (int j = 0; j < 4; ++j) { acc0[i][j] = 0.f; acc1[i][j] = 0.f; }

    for (int i = tid; i < 64 * K; i += 256) {
        int r = i / K;
        int k = i - r * K;
        int row = row0 + r;
        xs[k][r] = (row < NN) ? x[(size_t)row * K + k] : 0.f;
    }
    for (int i = tid; i < K * 64; i += 256) {
        int k = i >> 6;
        int cq = i & 63;
        const float* srcp = (cq < 32) ? &Wl1[(size_t)k * 128 + cq * 4]
                                      : &Wr1[(size_t)k * 128 + (cq - 32) * 4];
        float4 v = *(const float4*)srcp;
        *(float4*)&ws[k][cq * 4] = v;
    }
    __syncthreads();
    for (int k = 0; k < K; ++k) {
        float4 a0 = *(float4*)&xs[k][row_t];
        float4 a1 = *(float4*)&xs[k][row_t + 4];
        float4 b0 = *(float4*)&ws[k][c0];
        float4 b1 = *(float4*)&ws[k][c0 + 128];
        float av[8] = {a0.x, a0.y, a0.z, a0.w, a1.x, a1.y, a1.z, a1.w};
        float bl[4] = {b0.x, b0.y, b0.z, b0.w};
        float br[4] = {b1.x, b1.y, b1.z, b1.w};
#pragma unroll
        for (int i = 0; i < 8; ++i)
#pragma unroll
            for (int j = 0; j < 4; ++j) {
                acc0[i][j] += av[i] * bl[j];
                acc1[i][j] += av[i] * br[j];
            }
    }
#pragma unroll
    for (int i = 0; i < 8; ++i) {
        int row = row0 + row_t + i;
        if (row < NN) {
            store_xlp(xlp, row, c0, acc0[i]);
            float4 o1; o1.x = acc1[i][0]; o1.y = acc1[i][1]; o1.z = acc1[i][2]; o1.w = acc1[i][3];
            *(float4*)&xr[(size_t)row * HC + c0] = o1;
        }
    }
}

// ---- shared helper: reduce 64 stat buckets -> cf[128] in LDS/global ----
// Caller provides part[4][128] LDS. Wave w reduces buckets 16w..16w+15.
__device__ __forceinline__ void reduce_stats(const float* __restrict__ stats,
                                             const float* __restrict__ gw,
                                             const float* __restrict__ gb,
                                             const float* __restrict__ gm,
                                             float (*part)[128],
                                             float* __restrict__ cf_out) {
    int tid = threadIdx.x;
    int w = tid >> 6;
    int lane = tid & 63;
    float s = 0.f, s2 = 0.f;
    for (int b = 16 * w; b < 16 * w + 16; ++b) {
        s += stats[b * 128 + lane];
        s2 += stats[b * 128 + 64 + lane];
    }
    part[w][lane] = s;
    part[w][64 + lane] = s2;
    __syncthreads();
    if (tid < 64) {
        int c = tid;
        float sum = (part[0][c] + part[1][c]) + (part[2][c] + part[3][c]);
        float sum2 = (part[0][64 + c] + part[1][64 + c]) + (part[2][64 + c] + part[3][64 + c]);
        float inv_n = 1.f / (float)NN;
        float mu = sum * inv_n;
        float ex2 = sum2 * inv_n;
        float g = gm[c];
        float var = ex2 - 2.f * g * mu * mu + g * g * mu * mu;
        float rs = rsqrtf(var + EPSV);
        cf_out[c] = gw[c] * rs;
        cf_out[64 + c] = gb[c] - gw[c] * rs * g * mu;
    }
    __syncthreads();
}

// ---------------- MFMA bf16 GEMM, prologue computes cf from stat buckets ----------------

__global__ __launch_bounds__(256) void gemm_mfma(const float* __restrict__ h,
                                                 const float* __restrict__ stats,
                                                 const float* __restrict__ gw,
                                                 const float* __restrict__ gb,
                                                 const float* __restrict__ gm,
                                                 const unsigned short* __restrict__ wt,
                                                 char* __restrict__ xlp,
                                                 float* __restrict__ xr,
                                                 int n) {
    __shared__ unsigned short xs[64][72];
    __shared__ float part[4][128];
    __shared__ float cfS[128];
    int tid = threadIdx.x;
    int row0 = blockIdx.x * 64;

    reduce_stats(stats, gw, gb, gm, part, cfS);

    {
        int r = tid >> 2;
        int q = tid & 3;
        int row = row0 + r;
        unsigned pk[8];
        if (row < n) {
            const float* hp = h + (size_t)row * 64 + q * 16;
#pragma unroll
            for (int i = 0; i < 4; ++i) {
                float4 v = *(const float4*)(hp + 4 * i);
                float4 cw = *(const float4*)&cfS[q * 16 + 4 * i];
                float4 cb = *(const float4*)&cfS[64 + q * 16 + 4 * i];
                float r0 = fmaxf(fmaf(cw.x, v.x, cb.x), 0.f);
                float r1 = fmaxf(fmaf(cw.y, v.y, cb.y), 0.f);
                float r2 = fmaxf(fmaf(cw.z, v.z, cb.z), 0.f);
                float r3 = fmaxf(fmaf(cw.w, v.w, cb.w), 0.f);
                pk[2 * i]     = (unsigned)f2bf(r0) | ((unsigned)f2bf(r1) << 16);
                pk[2 * i + 1] = (unsigned)f2bf(r2) | ((unsigned)f2bf(r3) << 16);
            }
        } else {
#pragma unroll
            for (int i = 0; i < 8; ++i) pk[i] = 0;
        }
        uint4* dst = (uint4*)&xs[r][q * 16];
        dst[0] = make_uint4(pk[0], pk[1], pk[2], pk[3]);
        dst[1] = make_uint4(pk[4], pk[5], pk[6], pk[7]);
    }
    __syncthreads();

    int w = tid >> 6;
    int lane = tid & 63;
    int m = lane & 15;
    int quad = lane >> 4;

    BfU a0, a1;
    a0.u = *(const uint4*)&xs[16 * w + m][quad * 8];
    a1.u = *(const uint4*)&xs[16 * w + m][32 + quad * 8];

    const char* wtb = (const char*)wt + (size_t)(m * 128 + quad * 16);

    f32x4 acc[16];
#pragma unroll
    for (int c = 0; c < 16; ++c) acc[c] = (f32x4){0.f, 0.f, 0.f, 0.f};
#pragma unroll
    for (int c = 0; c < 16; ++c) {
        BfU b0, b1;
        b0.u = *(const uint4*)(wtb + c * 2048);
        b1.u = *(const uint4*)(wtb + c * 2048 + 64);
        acc[c] = __builtin_amdgcn_mfma_f32_16x16x32_bf16(a0.b, b0.b, acc[c], 0, 0, 0);
        acc[c] = __builtin_amdgcn_mfma_f32_16x16x32_bf16(a1.b, b1.b, acc[c], 0, 0, 0);
    }

    int rbase = row0 + 16 * w + quad * 4;
#pragma unroll
    for (int c = 8; c < 16; ++c) {
        int colx = 16 * (c - 8) + m;
#pragma unroll
        for (int r = 0; r < 4; ++r) {
            int row = rbase + r;
            if (row < n) xr[(size_t)row * 128 + colx] = acc[c][r];
        }
    }
#pragma unroll
    for (int pi = 0; pi < 4; ++pi) {
        int c = (pi & 1) + (pi >> 1) * 4;
        int head = pi >> 1;
        int dd = (pi & 1) * 16 + m;
#pragma unroll
        for (int r = 0; r < 4; ++r) {
            int row = rbase + r;
            if (row < n) {
                unsigned val = (unsigned)f2bf(acc[c][r]) | ((unsigned)f2bf(acc[c + 2][r]) << 16);
                *(unsigned*)(xlp + (size_t)row * 256 + head * 128 + 4 * dd) = val;
            }
        }
    }
}

// ---------------- coef_k: one block, stats buckets -> cf (for apply) ----------------

__global__ __launch_bounds__(256) void coef_k(const float* __restrict__ stats,
                                              const float* __restrict__ gw,
                                              const float* __restrict__ gb,
                                              const float* __restrict__ gm,
                                              float* __restrict__ cf) {
    __shared__ float part[4][128];
    reduce_stats(stats, gw, gb, gm, part, cf);
}

// ---------------- Attention + bucket-atomic stats epilogue (NO fence, NO ticket) ----------------

__device__ __forceinline__ void attn_batch(const char* __restrict__ xlp, int lp4,
                                           const int* offs, float2 xrv,
                                           float2 c1, float2 c2,
                                           bool b16, int my, int rem,
                                           float& zacc, float2& o) {
    unsigned pk[8];
#pragma unroll
    for (int j = 0; j < 8; ++j)
        pk[j] = *(const unsigned*)(xlp + (unsigned)(offs[j] + lp4));
    float2 l[8];
#pragma unroll
    for (int j = 0; j < 8; ++j) {
        l[j].x = __uint_as_float(pk[j] << 16);
        l[j].y = __uint_as_float(pk[j] & 0xffff0000u);
    }
    float u[8];
#pragma unroll
    for (int j = 0; j < 8; ++j) {
        float2 t; t.x = l[j].x + xrv.x; t.y = l[j].y + xrv.y;
        float2 q;
        q.x = fmaf(c1.x, t.x, c2.x * fabsf(t.x));
        q.y = fmaf(c1.y, t.y, c2.y * fabsf(t.y));
        u[j] = q.x + q.y;
    }
#pragma unroll
    for (int j = 0; j < 8; ++j) u[j] += __shfl_xor(u[j], 16, 64);
    float w0 = b16 ? u[0] : u[1];
    float w1 = b16 ? u[2] : u[3];
    float w2 = b16 ? u[4] : u[5];
    float w3 = b16 ? u[6] : u[7];
#pragma unroll
    for (int off = 8; off > 0; off >>= 1) {
        w0 += __shfl_xor(w0, off, 64);
        w1 += __shfl_xor(w1, off, 64);
        w2 += __shfl_xor(w2, off, 64);
        w3 += __shfl_xor(w3, off, 64);
    }
    float e0 = __expf(w0);
    float e1 = __expf(w1);
    float e2 = __expf(w2);
    float e3 = __expf(w3);
    if (rem < 8) {
        if (my >= rem)     e0 = 0.f;
        if (2 + my >= rem) e1 = 0.f;
        if (4 + my >= rem) e2 = 0.f;
        if (6 + my >= rem) e3 = 0.f;
    }
    zacc += (e0 + e1) + (e2 + e3);
    float s0 = __shfl_xor(e0, 16, 64);
    float s1 = __shfl_xor(e1, 16, 64);
    float s2 = __shfl_xor(e2, 16, 64);
    float s3 = __shfl_xor(e3, 16, 64);
    float p0 = b16 ? e0 : s0;
    float p1 = b16 ? s0 : e0;
    float p2 = b16 ? e1 : s1;
    float p3 = b16 ? s1 : e1;
    float p4 = b16 ? e2 : s2;
    float p5 = b16 ? s2 : e2;
    float p6 = b16 ? e3 : s3;
    float p7 = b16 ? s3 : e3;
    o.x = fmaf(p0, l[0].x, o.x); o.y = fmaf(p0, l[0].y, o.y);
    o.x = fmaf(p1, l[1].x, o.x); o.y = fmaf(p1, l[1].y, o.y);
    o.x = fmaf(p2, l[2].x, o.x); o.y = fmaf(p2, l[2].y, o.y);
    o.x = fmaf(p3, l[3].x, o.x); o.y = fmaf(p3, l[3].y, o.y);
    o.x = fmaf(p4, l[4].x, o.x); o.y = fmaf(p4, l[4].y, o.y);
    o.x = fmaf(p5, l[5].x, o.x); o.y = fmaf(p5, l[5].y, o.y);
    o.x = fmaf(p6, l[6].x, o.x); o.y = fmaf(p6, l[6].y, o.y);
    o.x = fmaf(p7, l[7].x, o.x); o.y = fmaf(p7, l[7].y, o.y);
}

__global__ __launch_bounds__(256) void attn_k(const char* __restrict__ xlp,
                                              const float* __restrict__ xr,
                                              const float* __restrict__ att,
                                              const float* __restrict__ bias,
                                              const int* __restrict__ row_ptr,
                                              const int* __restrict__ coloff,
                                              float* __restrict__ hout,
                                              float* __restrict__ stats) {
    __shared__ float sb[4][64];
    int tid = threadIdx.x;
    int lane = tid & 63;
    int w = tid >> 6;
    int node = blockIdx.x * 4 + w;        // grid == NN/4 exactly, no early return
    int laneh = lane & 31;
    int lanebase = ((lane >> 5) << 8) | (laneh << 2);
    bool b16 = (lane & 16) == 0;
    int my = b16 ? 0 : 1;
    int lp4 = lane * 4;

    const char* xrc = (const char*)xr;
    unsigned nodeoff = (unsigned)node << 9;

    float2 xrv;
    xrv.x = *(const float*)(xrc + nodeoff + lanebase);
    xrv.y = *(const float*)(xrc + nodeoff + lanebase + 128);
    float a1 = att[lanebase >> 2];
    float a2 = att[(lanebase >> 2) + 32];
    float2 c1; c1.x = 0.6f * a1; c1.y = 0.6f * a2;
    float2 c2; c2.x = 0.4f * a1; c2.y = 0.4f * a2;

    float zacc = 0.f;
    float2 o; o.x = 0.f; o.y = 0.f;

    int beg = __builtin_amdgcn_readfirstlane(row_ptr[node]);
    int end = __builtin_amdgcn_readfirstlane(row_ptr[node + 1]);

    int idx = beg;
    for (; idx + 8 <= end; idx += 8) {
        int offs[8];
#pragma unroll
        for (int j = 0; j < 8; ++j) offs[j] = coloff[idx + j];
        attn_batch(xlp, lp4, offs, xrv, c1, c2, b16, my, 8, zacc, o);
    }
    if (idx < end) {
        int rem = end - idx;
        int end1 = end - 1;
        int offs[8];
#pragma unroll
        for (int j = 0; j < 8; ++j) offs[j] = coloff[min(idx + j, end1)];
        attn_batch(xlp, lp4, offs, xrv, c1, c2, b16, my, rem, zacc, o);
    }
    float z = zacc + __shfl_xor(zacc, 16, 64);
    float zi = 1.0f / z;
    float2 t; t.x = o.x * zi; t.y = o.y * zi;
    float u1 = __shfl_xor(t.x, 32, 64);
    float u2 = __shfl_xor(t.y, 32, 64);
    if (lane < 32) {
        float r1 = fmaf(0.5f, t.x + u1, bias[laneh]);
        float r2 = fmaf(0.5f, t.y + u2, bias[laneh + 32]);
        float* q = hout + (size_t)node * 64 + laneh;
        q[0] = r1;
        q[32] = r2;
        sb[w][laneh] = r1;
        sb[w][laneh + 32] = r2;
    }
    // bucketed stats: atomicAdd and exit. Kernel completion publishes the values;
    // the consumer kernel (stream-ordered) reduces the buckets. NO fence/ticket.
    __syncthreads();
    if (tid < 64) {
        int c = tid;
        float v0 = sb[0][c], v1 = sb[1][c], v2 = sb[2][c], v3 = sb[3][c];
        float s = (v0 + v1) + (v2 + v3);
        float s2 = fmaf(v0, v0, v1 * v1) + fmaf(v2, v2, v3 * v3);
        float* bkt = stats + (size_t)(blockIdx.x & (NBUCK - 1)) * 128;
        atomicAdd(&bkt[c], s);
        atomicAdd(&bkt[64 + c], s2);
    }
}

// ---------------- final GraphNorm apply + ReLU (float4) ----------------

__global__ __launch_bounds__(256) void apply_k(const float* __restrict__ h,
                                               const float* __restrict__ cf,
                                               float* __restrict__ y) {
    int i = blockIdx.x * 256 + threadIdx.x;
    if (i >= NN * 16) return;
    int c = (i * 4) & 63;
    float4 v = *(const float4*)&h[(size_t)i * 4];
    float4 cw = *(const float4*)&cf[c];
    float4 cb = *(const float4*)&cf[64 + c];
    float4 r;
    r.x = fmaxf(fmaf(cw.x, v.x, cb.x), 0.f);
    r.y = fmaxf(fmaf(cw.y, v.y, cb.y), 0.f);
    r.z = fmaxf(fmaf(cw.z, v.z, cb.z), 0.f);
    r.w = fmaxf(fmaf(cw.w, v.w, cb.w), 0.f);
    *(float4*)&y[(size_t)i * 4] = r;
}

// ---------------- launch ----------------

extern "C" void kernel_launch(void* const* d_in, const int* in_sizes, int n_in,
                              void* d_out, int out_size, void* d_ws, size_t ws_size,
                              hipStream_t stream) {
    const float* x0 = (const float*)d_in[0];
    const int* ei = (const int*)d_in[1];
    const int* srcp = ei;
    const int* dstp = ei + NE;

    const float* Wl[3], *Wr[3], *att[3], *bv[3], *gw[3], *gb[3], *gm[3];
    for (int l = 0; l < 3; ++l) {
        int base = 2 + 7 * l;
        Wl[l] = (const float*)d_in[base + 0];
        Wr[l] = (const float*)d_in[base + 1];
        att[l] = (const float*)d_in[base + 2];
        bv[l] = (const float*)d_in[base + 3];
        gw[l] = (const float*)d_in[base + 4];
        gb[l] = (const float*)d_in[base + 5];
        gm[l] = (const float*)d_in[base + 6];
    }

    char* p = (char*)d_ws;
    auto take = [&](size_t bytes) -> void* {
        void* r = (void*)p;
        p += (bytes + 255) & ~(size_t)255;
        return r;
    };
    char* xlp = (char*)take((size_t)NN * 256);
    float* xr = (float*)take((size_t)NN * 128 * 4);
    float* hb = (float*)take((size_t)NN * 64 * 4);
    // zero region: stats buckets (3 * 64 * 128 f = 98304 B) + cnt (200000 B) = 298304 B
    char* zr = (char*)take(298304);
    float* stats = (float*)zr;
    int* cnt = (int*)(zr + 98304);
    int* excl = (int*)take((size_t)NN * 4);
    int* row_ptr = (int*)take((size_t)(NN + 1) * 4);
    int* rank = (int*)take((size_t)TE * 4);
    int* col = (int*)take((size_t)TE * 4);
    int* aux = (int*)take(64 * 4);
    float* cf3 = (float*)take(128 * 4);
    unsigned short* wt2 = (unsigned short*)take(16384 * 2);
    unsigned short* wt3 = (unsigned short*)take(16384 * 2);

    int nblk = (NN + 1023) / 1024;
    int egrid = (TE + 255) / 256;

    init_k<<<GGRID + WTB + ZB, 256, 0, stream>>>(x0, Wl[0], Wr[0], xlp, xr,
                                                 Wl[1], Wr[1], Wl[2], Wr[2],
                                                 wt2, wt3, (float4*)zr);
    count_k<<<egrid, 256, 0, stream>>>(dstp, cnt, rank);
    scan1_k<<<nblk, 1024, 0, stream>>>(cnt, excl, aux);
    scatter_k<<<egrid, 256, 0, stream>>>(srcp, dstp, excl, aux, rank, row_ptr, col, nblk);

    int ggrid = (NN + 63) / 64;
    int agrid = NN / 4;   // exact
    for (int l = 0; l < 3; ++l) {
        if (l > 0)
            gemm_mfma<<<ggrid, 256, 0, stream>>>(hb, stats + (size_t)(l - 1) * NBUCK * 128,
                                                 gw[l - 1], gb[l - 1], gm[l - 1],
                                                 (l == 1) ? wt2 : wt3, xlp, xr, NN);
        attn_k<<<agrid, 256, 0, stream>>>(xlp, xr, att[l], bv[l], row_ptr, col, hb,
                                          stats + (size_t)l * NBUCK * 128);
    }
    coef_k<<<1, 256, 0, stream>>>(stats + (size_t)2 * NBUCK * 128, gw[2], gb[2], gm[2], cf3);
    apply_k<<<(NN * 16 + 255) / 256, 256, 0, stream>>>(hb, cf3, (float*)d_out);
}

// Round 17
// 360.055 us; speedup vs baseline: 9.6243x; 1.0048x over previous
//
#include <hip/hip_runtime.h>
#include <math.h>

#define NN 50000
#define NE 800000
#define TE (NE + NN)
#define HC 128
#define NEG_SLOPE 0.2f
#define EPSV 1e-5f
#define NBUCK 64
#define GGRID 782          // (NN+63)/64 blocks for gemm_dual part of init_k
#define WTB 128            // wtrans blocks
#define ZB 52              // zero blocks
#define ZERO_N4 18644      // float4 count of zero region (298304 B = stats 98304 + cnt 200000)

typedef __attribute__((ext_vector_type(8))) short bf16x8;
typedef __attribute__((ext_vector_type(4))) float f32x4;
union BfU { uint4 u; bf16x8 b; };

__device__ __forceinline__ unsigned short f2bf(float x) {
    unsigned u = __float_as_uint(x);
    unsigned r = (u + 0x7fff + ((u >> 16) & 1)) >> 16;  // RNE
    return (unsigned short)r;
}

// ---------------- CSR build ----------------

__global__ __launch_bounds__(256) void count_k(const int* __restrict__ dst,
                                               int* __restrict__ cnt,
                                               int* __restrict__ rank) {
    int e = blockIdx.x * 256 + threadIdx.x;
    if (e >= TE) return;
    int d = (e < NE) ? dst[e] : (e - NE);
    rank[e] = atomicAdd(&cnt[d], 1);
}

__global__ __launch_bounds__(1024) void scan1_k(const int* __restrict__ cnt,
                                                int* __restrict__ excl,
                                                int* __restrict__ aux) {
    __shared__ int wsum[16];
    int tid = threadIdx.x;
    int gid = blockIdx.x * 1024 + tid;
    int lane = tid & 63, wid = tid >> 6;
    int v = (gid < NN) ? cnt[gid] : 0;
    int x = v;
#pragma unroll
    for (int off = 1; off < 64; off <<= 1) {
        int t = __shfl_up(x, off, 64);
        if (lane >= off) x += t;
    }
    if (lane == 63) wsum[wid] = x;
    __syncthreads();
    if (wid == 0 && lane < 16) {
        int y = wsum[lane];
#pragma unroll
        for (int off = 1; off < 16; off <<= 1) {
            int t = __shfl_up(y, off, 64);
            if (lane >= off) y += t;
        }
        wsum[lane] = y;
    }
    __syncthreads();
    int base = (wid > 0) ? wsum[wid - 1] : 0;
    int incl = base + x;
    if (gid < NN) excl[gid] = incl - v;
    if (tid == 1023) aux[blockIdx.x] = incl;
}

__global__ __launch_bounds__(256) void scatter_k(const int* __restrict__ srcp,
                                                 const int* __restrict__ dstp,
                                                 const int* __restrict__ excl,
                                                 const int* __restrict__ aux,
                                                 const int* __restrict__ rank,
                                                 int* __restrict__ row_ptr,
                                                 int* __restrict__ col,
                                                 int nblk) {
    __shared__ int auxs[64];
    if (threadIdx.x < 64) {
        int lane = threadIdx.x;
        int v = (lane < nblk) ? aux[lane] : 0;
        int x = v;
#pragma unroll
        for (int off = 1; off < 64; off <<= 1) {
            int t = __shfl_up(x, off, 64);
            if (lane >= off) x += t;
        }
        auxs[lane] = x - v;
    }
    __syncthreads();
    int e = blockIdx.x * 256 + threadIdx.x;
    if (e >= TE) return;
    if (e <= NN) row_ptr[e] = (e == NN) ? TE : excl[e] + auxs[e >> 10];
    int s, d;
    if (e < NE) { s = srcp[e]; d = dstp[e]; } else { s = e - NE; d = s; }
    col[excl[d] + auxs[d >> 10] + rank[e]] = s << 8;
}

// ---- packed xl epilogue store (fp32 path, layer 1) ----
__device__ __forceinline__ void store_xlp(char* xlp, int row, int c0, const float* a) {
    unsigned hsel = (unsigned)c0 >> 6;
    unsigned dd = (unsigned)c0 & 31;
    unsigned sub = (c0 & 32) ? 2u : 0u;
    char* q = xlp + (size_t)row * 256 + hsel * 128 + 4 * dd + sub;
#pragma unroll
    for (int j = 0; j < 4; ++j)
        *(unsigned short*)(q + 4 * j) = f2bf(a[j]);
}

// ---------------- init_k: gemm_dual (layer1) + wtrans + zero, block-range split ----------------

__global__ __launch_bounds__(256) void init_k(const float* __restrict__ x,
                                              const float* __restrict__ Wl1,
                                              const float* __restrict__ Wr1,
                                              char* __restrict__ xlp,
                                              float* __restrict__ xr,
                                              const float* __restrict__ Wl2,
                                              const float* __restrict__ Wr2,
                                              const float* __restrict__ Wl3,
                                              const float* __restrict__ Wr3,
                                              unsigned short* __restrict__ wt2,
                                              unsigned short* __restrict__ wt3,
                                              float4* __restrict__ zero4) {
    __shared__ float xs[32][72];
    __shared__ float ws[32][260];
    int b = blockIdx.x;
    int tid = threadIdx.x;

    if (b >= GGRID) {
        if (b < GGRID + WTB) {
            int idx = (b - GGRID) * 256 + tid;
            int l = idx >> 14;
            int rem = idx & 16383;
            int k = rem >> 8;
            int c = rem & 255;
            const float* W = (l == 0) ? (c < 128 ? Wl2 : Wr2) : (c < 128 ? Wl3 : Wr3);
            float v = W[k * 128 + (c & 127)];
            unsigned short* wt = (l == 0) ? wt2 : wt3;
            wt[c * 64 + k] = f2bf(v);
        } else {
            float4 zv; zv.x = zv.y = zv.z = zv.w = 0.f;
            for (int i = (b - GGRID - WTB) * 256 + tid; i < ZERO_N4; i += ZB * 256)
                zero4[i] = zv;
        }
        return;
    }

    // ---- gemm_dual body (K=3) ----
    int row0 = b * 64;
    int row_t = (tid >> 5) * 8;
    int c0 = (tid & 31) * 4;
    const int K = 3;

    float acc0[8][4];
    float acc1[8][4];
#pragma unroll
    for (int i = 0; i < 8; ++i)
#pragma unroll
        for (int j = 0; j < 4; ++j) { acc0[i][j] = 0.f; acc1[i][j] = 0.f; }

    for (int i = tid; i < 64 * K; i += 256) {
        int r = i / K;
        int k = i - r * K;
        int row = row0 + r;
        xs[k][r] = (row < NN) ? x[(size_t)row * K + k] : 0.f;
    }
    for (int i = tid; i < K * 64; i += 256) {
        int k = i >> 6;
        int cq = i & 63;
        const float* srcp = (cq < 32) ? &Wl1[(size_t)k * 128 + cq * 4]
                                      : &Wr1[(size_t)k * 128 + (cq - 32) * 4];
        float4 v = *(const float4*)srcp;
        *(float4*)&ws[k][cq * 4] = v;
    }
    __syncthreads();
    for (int k = 0; k < K; ++k) {
        float4 a0 = *(float4*)&xs[k][row_t];
        float4 a1 = *(float4*)&xs[k][row_t + 4];
        float4 b0 = *(float4*)&ws[k][c0];
        float4 b1 = *(float4*)&ws[k][c0 + 128];
        float av[8] = {a0.x, a0.y, a0.z, a0.w, a1.x, a1.y, a1.z, a1.w};
        float bl[4] = {b0.x, b0.y, b0.z, b0.w};
        float br[4] = {b1.x, b1.y, b1.z, b1.w};
#pragma unroll
        for (int i = 0; i < 8; ++i)
#pragma unroll
            for (int j = 0; j < 4; ++j) {
                acc0[i][j] += av[i] * bl[j];
                acc1[i][j] += av[i] * br[j];
            }
    }
#pragma unroll
    for (int i = 0; i < 8; ++i) {
        int row = row0 + row_t + i;
        if (row < NN) {
            store_xlp(xlp, row, c0, acc0[i]);
            float4 o1; o1.x = acc1[i][0]; o1.y = acc1[i][1]; o1.z = acc1[i][2]; o1.w = acc1[i][3];
            *(float4*)&xr[(size_t)row * HC + c0] = o1;
        }
    }
}

// ---- shared helper: reduce 64 stat buckets -> cf[128] ----
__device__ __forceinline__ void reduce_stats(const float* __restrict__ stats,
                                             const float* __restrict__ gw,
                                             const float* __restrict__ gb,
                                             const float* __restrict__ gm,
                                             float (*part)[128],
                                             float* __restrict__ cf_out) {
    int tid = threadIdx.x;
    int w = tid >> 6;
    int lane = tid & 63;
    float s = 0.f, s2 = 0.f;
    for (int b = 16 * w; b < 16 * w + 16; ++b) {
        s += stats[b * 128 + lane];
        s2 += stats[b * 128 + 64 + lane];
    }
    part[w][lane] = s;
    part[w][64 + lane] = s2;
    __syncthreads();
    if (tid < 64) {
        int c = tid;
        float sum = (part[0][c] + part[1][c]) + (part[2][c] + part[3][c]);
        float sum2 = (part[0][64 + c] + part[1][64 + c]) + (part[2][64 + c] + part[3][64 + c]);
        float inv_n = 1.f / (float)NN;
        float mu = sum * inv_n;
        float ex2 = sum2 * inv_n;
        float g = gm[c];
        float var = ex2 - 2.f * g * mu * mu + g * g * mu * mu;
        float rs = rsqrtf(var + EPSV);
        cf_out[c] = gw[c] * rs;
        cf_out[64 + c] = gb[c] - gw[c] * rs * g * mu;
    }
    __syncthreads();
}

// ---------------- MFMA bf16 GEMM; h input is packed bf16 (col c, c+32 per uint) ----------------

__global__ __launch_bounds__(256) void gemm_mfma(const unsigned* __restrict__ hbf,
                                                 const float* __restrict__ stats,
                                                 const float* __restrict__ gw,
                                                 const float* __restrict__ gb,
                                                 const float* __restrict__ gm,
                                                 const unsigned short* __restrict__ wt,
                                                 char* __restrict__ xlp,
                                                 float* __restrict__ xr,
                                                 int n) {
    __shared__ unsigned short xs[64][72];
    __shared__ float part[4][128];
    __shared__ float cfS[128];
    int tid = threadIdx.x;
    int row0 = blockIdx.x * 64;

    reduce_stats(stats, gw, gb, gm, part, cfS);

    {
        int r = tid >> 2;
        int q = tid & 3;
        int row = row0 + r;
        unsigned pk[8];
        if (row < n) {
            const unsigned* hp = hbf + (size_t)row * 32 + (q & 1) * 16;
            uint4 u0 = *(const uint4*)(hp + 0);
            uint4 u1 = *(const uint4*)(hp + 4);
            uint4 u2 = *(const uint4*)(hp + 8);
            uint4 u3 = *(const uint4*)(hp + 12);
            unsigned hv[16] = {u0.x, u0.y, u0.z, u0.w, u1.x, u1.y, u1.z, u1.w,
                               u2.x, u2.y, u2.z, u2.w, u3.x, u3.y, u3.z, u3.w};
            bool hi = (q >> 1) != 0;
#pragma unroll
            for (int i = 0; i < 4; ++i) {
                float4 v;
                v.x = hi ? __uint_as_float(hv[4 * i + 0] & 0xffff0000u) : __uint_as_float(hv[4 * i + 0] << 16);
                v.y = hi ? __uint_as_float(hv[4 * i + 1] & 0xffff0000u) : __uint_as_float(hv[4 * i + 1] << 16);
                v.z = hi ? __uint_as_float(hv[4 * i + 2] & 0xffff0000u) : __uint_as_float(hv[4 * i + 2] << 16);
                v.w = hi ? __uint_as_float(hv[4 * i + 3] & 0xffff0000u) : __uint_as_float(hv[4 * i + 3] << 16);
                float4 cw = *(const float4*)&cfS[q * 16 + 4 * i];
                float4 cb = *(const float4*)&cfS[64 + q * 16 + 4 * i];
                float r0 = fmaxf(fmaf(cw.x, v.x, cb.x), 0.f);
                float r1 = fmaxf(fmaf(cw.y, v.y, cb.y), 0.f);
                float r2 = fmaxf(fmaf(cw.z, v.z, cb.z), 0.f);
                float r3 = fmaxf(fmaf(cw.w, v.w, cb.w), 0.f);
                pk[2 * i]     = (unsigned)f2bf(r0) | ((unsigned)f2bf(r1) << 16);
                pk[2 * i + 1] = (unsigned)f2bf(r2) | ((unsigned)f2bf(r3) << 16);
            }
        } else {
#pragma unroll
            for (int i = 0; i < 8; ++i) pk[i] = 0;
        }
        uint4* dst = (uint4*)&xs[r][q * 16];
        dst[0] = make_uint4(pk[0], pk[1], pk[2], pk[3]);
        dst[1] = make_uint4(pk[4], pk[5], pk[6], pk[7]);
    }
    __syncthreads();

    int w = tid >> 6;
    int lane = tid & 63;
    int m = lane & 15;
    int quad = lane >> 4;

    BfU a0, a1;
    a0.u = *(const uint4*)&xs[16 * w + m][quad * 8];
    a1.u = *(const uint4*)&xs[16 * w + m][32 + quad * 8];

    const char* wtb = (const char*)wt + (size_t)(m * 128 + quad * 16);

    f32x4 acc[16];
#pragma unroll
    for (int c = 0; c < 16; ++c) acc[c] = (f32x4){0.f, 0.f, 0.f, 0.f};
#pragma unroll
    for (int c = 0; c < 16; ++c) {
        BfU b0, b1;
        b0.u = *(const uint4*)(wtb + c * 2048);
        b1.u = *(const uint4*)(wtb + c * 2048 + 64);
        acc[c] = __builtin_amdgcn_mfma_f32_16x16x32_bf16(a0.b, b0.b, acc[c], 0, 0, 0);
        acc[c] = __builtin_amdgcn_mfma_f32_16x16x32_bf16(a1.b, b1.b, acc[c], 0, 0, 0);
    }

    int rbase = row0 + 16 * w + quad * 4;
#pragma unroll
    for (int c = 8; c < 16; ++c) {
        int colx = 16 * (c - 8) + m;
#pragma unroll
        for (int r = 0; r < 4; ++r) {
            int row = rbase + r;
            if (row < n) xr[(size_t)row * 128 + colx] = acc[c][r];
        }
    }
#pragma unroll
    for (int pi = 0; pi < 4; ++pi) {
        int c = (pi & 1) + (pi >> 1) * 4;
        int head = pi >> 1;
        int dd = (pi & 1) * 16 + m;
#pragma unroll
        for (int r = 0; r < 4; ++r) {
            int row = rbase + r;
            if (row < n) {
                unsigned val = (unsigned)f2bf(acc[c][r]) | ((unsigned)f2bf(acc[c + 2][r]) << 16);
                *(unsigned*)(xlp + (size_t)row * 256 + head * 128 + 4 * dd) = val;
            }
        }
    }
}

// ---------------- coef_k: one block, stats buckets -> cf (for apply) ----------------

__global__ __launch_bounds__(256) void coef_k(const float* __restrict__ stats,
                                              const float* __restrict__ gw,
                                              const float* __restrict__ gb,
                                              const float* __restrict__ gm,
                                              float* __restrict__ cf) {
    __shared__ float part[4][128];
    reduce_stats(stats, gw, gb, gm, part, cf);
}

// ---------------- Attention + bucket-atomic stats epilogue (fence-free) ----------------

__device__ __forceinline__ void attn_batch(const char* __restrict__ xlp, int lp4,
                                           const int* offs, float2 xrv,
                                           float2 c1, float2 c2,
                                           bool b16, int my, int rem,
                                           float& zacc, float2& o) {
    unsigned pk[8];
#pragma unroll
    for (int j = 0; j < 8; ++j)
        pk[j] = *(const unsigned*)(xlp + (unsigned)(offs[j] + lp4));
    float2 l[8];
#pragma unroll
    for (int j = 0; j < 8; ++j) {
        l[j].x = __uint_as_float(pk[j] << 16);
        l[j].y = __uint_as_float(pk[j] & 0xffff0000u);
    }
    float u[8];
#pragma unroll
    for (int j = 0; j < 8; ++j) {
        float2 t; t.x = l[j].x + xrv.x; t.y = l[j].y + xrv.y;
        float2 q;
        q.x = fmaf(c1.x, t.x, c2.x * fabsf(t.x));
        q.y = fmaf(c1.y, t.y, c2.y * fabsf(t.y));
        u[j] = q.x + q.y;
    }
#pragma unroll
    for (int j = 0; j < 8; ++j) u[j] += __shfl_xor(u[j], 16, 64);
    float w0 = b16 ? u[0] : u[1];
    float w1 = b16 ? u[2] : u[3];
    float w2 = b16 ? u[4] : u[5];
    float w3 = b16 ? u[6] : u[7];
#pragma unroll
    for (int off = 8; off > 0; off >>= 1) {
        w0 += __shfl_xor(w0, off, 64);
        w1 += __shfl_xor(w1, off, 64);
        w2 += __shfl_xor(w2, off, 64);
        w3 += __shfl_xor(w3, off, 64);
    }
    float e0 = __expf(w0);
    float e1 = __expf(w1);
    float e2 = __expf(w2);
    float e3 = __expf(w3);
    if (rem < 8) {
        if (my >= rem)     e0 = 0.f;
        if (2 + my >= rem) e1 = 0.f;
        if (4 + my >= rem) e2 = 0.f;
        if (6 + my >= rem) e3 = 0.f;
    }
    zacc += (e0 + e1) + (e2 + e3);
    float s0 = __shfl_xor(e0, 16, 64);
    float s1 = __shfl_xor(e1, 16, 64);
    float s2 = __shfl_xor(e2, 16, 64);
    float s3 = __shfl_xor(e3, 16, 64);
    float p0 = b16 ? e0 : s0;
    float p1 = b16 ? s0 : e0;
    float p2 = b16 ? e1 : s1;
    float p3 = b16 ? s1 : e1;
    float p4 = b16 ? e2 : s2;
    float p5 = b16 ? s2 : e2;
    float p6 = b16 ? e3 : s3;
    float p7 = b16 ? s3 : e3;
    o.x = fmaf(p0, l[0].x, o.x); o.y = fmaf(p0, l[0].y, o.y);
    o.x = fmaf(p1, l[1].x, o.x); o.y = fmaf(p1, l[1].y, o.y);
    o.x = fmaf(p2, l[2].x, o.x); o.y = fmaf(p2, l[2].y, o.y);
    o.x = fmaf(p3, l[3].x, o.x); o.y = fmaf(p3, l[3].y, o.y);
    o.x = fmaf(p4, l[4].x, o.x); o.y = fmaf(p4, l[4].y, o.y);
    o.x = fmaf(p5, l[5].x, o.x); o.y = fmaf(p5, l[5].y, o.y);
    o.x = fmaf(p6, l[6].x, o.x); o.y = fmaf(p6, l[6].y, o.y);
    o.x = fmaf(p7, l[7].x, o.x); o.y = fmaf(p7, l[7].y, o.y);
}

__global__ __launch_bounds__(256) void attn_k(const char* __restrict__ xlp,
                                              const float* __restrict__ xr,
                                              const float* __restrict__ att,
                                              const float* __restrict__ bias,
                                              const int* __restrict__ row_ptr,
                                              const int* __restrict__ coloff,
                                              unsigned* __restrict__ hout,
                                              float* __restrict__ stats) {
    __shared__ float sb[4][64];
    int tid = threadIdx.x;
    int lane = tid & 63;
    int w = tid >> 6;
    int node = blockIdx.x * 4 + w;        // grid == NN/4 exactly, no early return
    int laneh = lane & 31;
    int lanebase = ((lane >> 5) << 8) | (laneh << 2);
    bool b16 = (lane & 16) == 0;
    int my = b16 ? 0 : 1;
    int lp4 = lane * 4;

    const char* xrc = (const char*)xr;
    unsigned nodeoff = (unsigned)node << 9;

    float2 xrv;
    xrv.x = *(const float*)(xrc + nodeoff + lanebase);
    xrv.y = *(const float*)(xrc + nodeoff + lanebase + 128);
    float a1 = att[lanebase >> 2];
    float a2 = att[(lanebase >> 2) + 32];
    float2 c1; c1.x = 0.6f * a1; c1.y = 0.6f * a2;
    float2 c2; c2.x = 0.4f * a1; c2.y = 0.4f * a2;

    float zacc = 0.f;
    float2 o; o.x = 0.f; o.y = 0.f;

    int beg = __builtin_amdgcn_readfirstlane(row_ptr[node]);
    int end = __builtin_amdgcn_readfirstlane(row_ptr[node + 1]);

    int idx = beg;
    for (; idx + 8 <= end; idx += 8) {
        int offs[8];
#pragma unroll
        for (int j = 0; j < 8; ++j) offs[j] = coloff[idx + j];
        attn_batch(xlp, lp4, offs, xrv, c1, c2, b16, my, 8, zacc, o);
    }
    if (idx < end) {
        int rem = end - idx;
        int end1 = end - 1;
        int offs[8];
#pragma unroll
        for (int j = 0; j < 8; ++j) offs[j] = coloff[min(idx + j, end1)];
        attn_batch(xlp, lp4, offs, xrv, c1, c2, b16, my, rem, zacc, o);
    }
    float z = zacc + __shfl_xor(zacc, 16, 64);
    float zi = 1.0f / z;
    float2 t; t.x = o.x * zi; t.y = o.y * zi;
    float u1 = __shfl_xor(t.x, 32, 64);
    float u2 = __shfl_xor(t.y, 32, 64);
    if (lane < 32) {
        float r1 = fmaf(0.5f, t.x + u1, bias[laneh]);
        float r2 = fmaf(0.5f, t.y + u2, bias[laneh + 32]);
        hout[(size_t)node * 32 + laneh] = (unsigned)f2bf(r1) | ((unsigned)f2bf(r2) << 16);
        sb[w][laneh] = r1;
        sb[w][laneh + 32] = r2;
    }
    __syncthreads();
    if (tid < 64) {
        int c = tid;
        float v0 = sb[0][c], v1 = sb[1][c], v2 = sb[2][c], v3 = sb[3][c];
        float s = (v0 + v1) + (v2 + v3);
        float s2 = fmaf(v0, v0, v1 * v1) + fmaf(v2, v2, v3 * v3);
        float* bkt = stats + (size_t)(blockIdx.x & (NBUCK - 1)) * 128;
        atomicAdd(&bkt[c], s);
        atomicAdd(&bkt[64 + c], s2);
    }
}

// ---------------- final GraphNorm apply + ReLU (unpack bf16 h, fp32 out) ----------------

__global__ __launch_bounds__(256) void apply_k(const unsigned* __restrict__ h,
                                               const float* __restrict__ cf,
                                               float* __restrict__ y) {
    int i = blockIdx.x * 256 + threadIdx.x;   // uint4 index, total NN*8
    if (i >= NN * 8) return;
    int node = i >> 3;
    int j = (i & 7) * 4;                      // laneh base 0,4,...,28
    uint4 u = *(const uint4*)(h + (size_t)node * 32 + j);
    float4 lo, hi;
    lo.x = __uint_as_float(u.x << 16); hi.x = __uint_as_float(u.x & 0xffff0000u);
    lo.y = __uint_as_float(u.y << 16); hi.y = __uint_as_float(u.y & 0xffff0000u);
    lo.z = __uint_as_float(u.z << 16); hi.z = __uint_as_float(u.z & 0xffff0000u);
    lo.w = __uint_as_float(u.w << 16); hi.w = __uint_as_float(u.w & 0xffff0000u);
    float4 cwl = *(const float4*)&cf[j];
    float4 cbl = *(const float4*)&cf[64 + j];
    float4 cwh = *(const float4*)&cf[32 + j];
    float4 cbh = *(const float4*)&cf[96 + j];
    float4 rl, rh;
    rl.x = fmaxf(fmaf(cwl.x, lo.x, cbl.x), 0.f);
    rl.y = fmaxf(fmaf(cwl.y, lo.y, cbl.y), 0.f);
    rl.z = fmaxf(fmaf(cwl.z, lo.z, cbl.z), 0.f);
    rl.w = fmaxf(fmaf(cwl.w, lo.w, cbl.w), 0.f);
    rh.x = fmaxf(fmaf(cwh.x, hi.x, cbh.x), 0.f);
    rh.y = fmaxf(fmaf(cwh.y, hi.y, cbh.y), 0.f);
    rh.z = fmaxf(fmaf(cwh.z, hi.z, cbh.z), 0.f);
    rh.w = fmaxf(fmaf(cwh.w, hi.w, cbh.w), 0.f);
    *(float4*)&y[(size_t)node * 64 + j] = rl;
    *(float4*)&y[(size_t)node * 64 + 32 + j] = rh;
}

// ---------------- launch ----------------

extern "C" void kernel_launch(void* const* d_in, const int* in_sizes, int n_in,
                              void* d_out, int out_size, void* d_ws, size_t ws_size,
                              hipStream_t stream) {
    const float* x0 = (const float*)d_in[0];
    const int* ei = (const int*)d_in[1];
    const int* srcp = ei;
    const int* dstp = ei + NE;

    const float* Wl[3], *Wr[3], *att[3], *bv[3], *gw[3], *gb[3], *gm[3];
    for (int l = 0; l < 3; ++l) {
        int base = 2 + 7 * l;
        Wl[l] = (const float*)d_in[base + 0];
        Wr[l] = (const float*)d_in[base + 1];
        att[l] = (const float*)d_in[base + 2];
        bv[l] = (const float*)d_in[base + 3];
        gw[l] = (const float*)d_in[base + 4];
        gb[l] = (const float*)d_in[base + 5];
        gm[l] = (const float*)d_in[base + 6];
    }

    char* p = (char*)d_ws;
    auto take = [&](size_t bytes) -> void* {
        void* r = (void*)p;
        p += (bytes + 255) & ~(size_t)255;
        return r;
    };
    char* xlp = (char*)take((size_t)NN * 256);
    float* xr = (float*)take((size_t)NN * 128 * 4);
    unsigned* hb = (unsigned*)take((size_t)NN * 32 * 4);   // packed bf16 hidden state
    char* zr = (char*)take(298304);
    float* stats = (float*)zr;
    int* cnt = (int*)(zr + 98304);
    int* excl = (int*)take((size_t)NN * 4);
    int* row_ptr = (int*)take((size_t)(NN + 1) * 4);
    int* rank = (int*)take((size_t)TE * 4);
    int* col = (int*)take((size_t)TE * 4);
    int* aux = (int*)take(64 * 4);
    float* cf3 = (float*)take(128 * 4);
    unsigned short* wt2 = (unsigned short*)take(16384 * 2);
    unsigned short* wt3 = (unsigned short*)take(16384 * 2);

    int nblk = (NN + 1023) / 1024;
    int egrid = (TE + 255) / 256;

    init_k<<<GGRID + WTB + ZB, 256, 0, stream>>>(x0, Wl[0], Wr[0], xlp, xr,
                                                 Wl[1], Wr[1], Wl[2], Wr[2],
                                                 wt2, wt3, (float4*)zr);
    count_k<<<egrid, 256, 0, stream>>>(dstp, cnt, rank);
    scan1_k<<<nblk, 1024, 0, stream>>>(cnt, excl, aux);
    scatter_k<<<egrid, 256, 0, stream>>>(srcp, dstp, excl, aux, rank, row_ptr, col, nblk);

    int ggrid = (NN + 63) / 64;
    int agrid = NN / 4;   // exact
    for (int l = 0; l < 3; ++l) {
        if (l > 0)
            gemm_mfma<<<ggrid, 256, 0, stream>>>(hb, stats + (size_t)(l - 1) * NBUCK * 128,
                                                 gw[l - 1], gb[l - 1], gm[l - 1],
                                                 (l == 1) ? wt2 : wt3, xlp, xr, NN);
        attn_k<<<agrid, 256, 0, stream>>>(xlp, xr, att[l], bv[l], row_ptr, col, hb,
                                          stats + (size_t)l * NBUCK * 128);
    }
    coef_k<<<1, 256, 0, stream>>>(stats + (size_t)2 * NBUCK * 128, gw[2], gb[2], gm[2], cf3);
    apply_k<<<(NN * 8 + 255) / 256, 256, 0, stream>>>(hb, cf3, (float*)d_out);
}